// Round 10
// baseline (717.510 us; speedup 1.0000x reference)
//
#include <hip/hip_runtime.h>
#include <hip/hip_bf16.h>

#define N_NODES 10000
#define N_EDGES 200000
#define TE 32   // edges per block in fused edge kernel (2 M-tiles of 16)

typedef __attribute__((ext_vector_type(8))) short short8;
typedef __attribute__((ext_vector_type(4))) float f32x4;

// Native converts: compiler emits v_cvt_pk_bf16_f32 (1 op / 2 floats).
static __device__ __forceinline__ ushort f2bf(float x) {
  union { __hip_bfloat16 h; ushort u; } v;
  v.h = __float2bfloat16(x);
  return v.u;
}
static __device__ __forceinline__ uint pk2bf(float lo, float hi) {
  union { __hip_bfloat162 h; uint u; } v;
  v.h = __float22bfloat162_rn(make_float2(lo, hi));
  return v.u;
}
static __device__ __forceinline__ float bf2f(ushort h) {
  union { uint u; float f; } v; v.u = ((uint)h) << 16;
  return v.f;
}

// ---------------------------------------------------------------------------
// All weight permutes in ONE launch.
// Each job: W[row0+k][ld] f32 -> Wp[kt][n0+n][k32] bf16 (dest Ntot cols).
// ---------------------------------------------------------------------------
__device__ __forceinline__ void permute_job(
    const float* W, ushort* Wp, int o, int K, int N, int ld,
    int row0, int n0, int Ntot)
{
  if (o >= K * N) return;
  int k = o & 31;
  int n = (o >> 5) % N;
  int kt = o / (N * 32);
  Wp[(size_t)kt * Ntot * 32 + (size_t)(n0 + n) * 32 + k] =
      f2bf(W[(size_t)(row0 + kt * 32 + k) * ld + n]);
}

__global__ __launch_bounds__(256) void permute_all(
    const float* __restrict__ We1, const float* __restrict__ We2,
    const float* __restrict__ Wn1, const float* __restrict__ Wee1,
    const float* __restrict__ Wee2, const float* __restrict__ Wec1,
    ushort* __restrict__ Wsp, ushort* __restrict__ W1ep,
    ushort* __restrict__ W2p, ushort* __restrict__ W3ep,
    ushort* __restrict__ Wee1p, ushort* __restrict__ Wee2p,
    ushort* __restrict__ Wec1p)
{
  int b = blockIdx.x, t = threadIdx.x;
  if (b < 512)       permute_job(We1, Wsp,  (b       ) * 256 + t, 256, 512, 512,   0,    0, 1152);
  else if (b < 1024) permute_job(We1, Wsp,  (b - 512 ) * 256 + t, 256, 512, 512, 256,  512, 1152);
  else if (b < 1152) permute_job(Wn1, Wsp,  (b - 1024) * 256 + t, 256, 128, 128,   0, 1024, 1152);
  else if (b < 1664) permute_job(We1, W1ep, (b - 1152) * 256 + t, 256, 512, 512, 512,    0,  512);
  else if (b < 1920) permute_job(We2, W2p,  (b - 1664) * 256 + t, 512, 128, 128,   0,    0,  128);
  else if (b < 1984) permute_job(Wn1, W3ep, (b - 1920) * 256 + t, 128, 128, 128, 256,    0,  128);
  else if (b < 2016) permute_job(Wee1, Wee1p,(b - 1984) * 256 + t,  64, 128, 128,   0,    0,  128);
  else if (b < 2080) permute_job(Wee2, Wee2p,(b - 2016) * 256 + t, 128, 128, 128,   0,    0,  128);
  else               permute_job(Wec1, Wec1p,(b - 2080) * 256 + t, 128, 128, 128,   0,    0,  128);
}

// ---------------------------------------------------------------------------
// Node embedding 2-layer MLP (f32 VALU; only 10K rows): bf16 outputs.
// ---------------------------------------------------------------------------
template <int K1>
__global__ __launch_bounds__(256) void mlp2_kernel(
    const float* __restrict__ in, int n_rows,
    const float* __restrict__ W1, const float* __restrict__ b1,
    const float* __restrict__ W2, const float* __restrict__ b2,
    ushort* __restrict__ out0, ushort* __restrict__ out1)
{
  __shared__ float s_a[8][K1];
  __shared__ float s_h[8][128];
  const int r0 = blockIdx.x * 8;
  const int t = threadIdx.x;

  for (int idx = t; idx < 8 * K1; idx += 256) {
    int r = idx / K1, k = idx - r * K1;
    int row = r0 + r;
    s_a[r][k] = (row < n_rows) ? in[(size_t)row * K1 + k] : 0.f;
  }
  __syncthreads();

  const int c = t & 127;
  const int g = t >> 7;
  float acc[4];
#pragma unroll
  for (int e = 0; e < 4; ++e) acc[e] = b1[c];
  for (int k = 0; k < K1; ++k) {
    float w = W1[(size_t)k * 128 + c];
#pragma unroll
    for (int e = 0; e < 4; ++e) acc[e] = fmaf(s_a[g * 4 + e][k], w, acc[e]);
  }
#pragma unroll
  for (int e = 0; e < 4; ++e) s_h[g * 4 + e][c] = fmaxf(acc[e], 0.f);
  __syncthreads();

#pragma unroll
  for (int e = 0; e < 4; ++e) acc[e] = b2[c];
  for (int k = 0; k < 128; ++k) {
    float w = W2[(size_t)k * 128 + c];
#pragma unroll
    for (int e = 0; e < 4; ++e) acc[e] = fmaf(s_h[g * 4 + e][k], w, acc[e]);
  }
#pragma unroll
  for (int e = 0; e < 4; ++e) {
    int row = r0 + g * 4 + e;
    if (row < n_rows) {
      ushort v = f2bf(fmaxf(acc[e], 0.f));
      out0[(size_t)row * 128 + c] = v;
      if (out1) out1[(size_t)row * 128 + c] = v;
    }
  }
}

// ---------------------------------------------------------------------------
// update MLP: out = relu(agg @ W + b), agg f32, out bf16 (10K rows).
// ---------------------------------------------------------------------------
__global__ __launch_bounds__(256) void mlp1_kernel(
    const float* __restrict__ in, int n_rows,
    const float* __restrict__ W, const float* __restrict__ b,
    ushort* __restrict__ out)
{
  __shared__ float s_a[8][128];
  const int r0 = blockIdx.x * 8;
  const int t = threadIdx.x;
  for (int idx = t; idx < 8 * 128; idx += 256) {
    int r = idx >> 7, k = idx & 127;
    int row = r0 + r;
    s_a[r][k] = (row < n_rows) ? in[(size_t)row * 128 + k] : 0.f;
  }
  __syncthreads();
  const int c = t & 127;
  const int g = t >> 7;
  float acc[4];
#pragma unroll
  for (int e = 0; e < 4; ++e) acc[e] = b[c];
  for (int k = 0; k < 128; ++k) {
    float w = W[(size_t)k * 128 + c];
#pragma unroll
    for (int e = 0; e < 4; ++e) acc[e] = fmaf(s_a[g * 4 + e][k], w, acc[e]);
  }
#pragma unroll
  for (int e = 0; e < 4; ++e) {
    int row = r0 + g * 4 + e;
    if (row < n_rows) out[(size_t)row * 128 + c] = f2bf(fmaxf(acc[e], 0.f));
  }
}

// ---------------------------------------------------------------------------
// Node classification head (10K rows, VALU).
// ---------------------------------------------------------------------------
__global__ __launch_bounds__(256) void cls_kernel(
    const ushort* __restrict__ feat, int n_rows,
    const float* __restrict__ W1, const float* __restrict__ b1,
    const float* __restrict__ W2, const float* __restrict__ b2,
    float* __restrict__ out)
{
  __shared__ float s_a[8][128];
  __shared__ float s_h[8][128];
  const int r0 = blockIdx.x * 8;
  const int t = threadIdx.x;
  for (int idx = t; idx < 8 * 128; idx += 256) {
    int r = idx >> 7, k = idx & 127;
    int row = r0 + r;
    s_a[r][k] = (row < n_rows) ? bf2f(feat[(size_t)row * 128 + k]) : 0.f;
  }
  __syncthreads();
  const int c = t & 127;
  const int g = t >> 7;
  float acc[4];
#pragma unroll
  for (int e = 0; e < 4; ++e) acc[e] = b1[c];
  for (int k = 0; k < 128; ++k) {
    float w = W1[(size_t)k * 128 + c];
#pragma unroll
    for (int e = 0; e < 4; ++e) acc[e] = fmaf(s_a[g * 4 + e][k], w, acc[e]);
  }
#pragma unroll
  for (int e = 0; e < 4; ++e) s_h[g * 4 + e][c] = fmaxf(acc[e], 0.f);
  __syncthreads();

  const int wave = t >> 6, lane = t & 63;
#pragma unroll
  for (int e2 = 0; e2 < 2; ++e2) {
    int r = wave * 2 + e2;
    float p = s_h[r][lane] * W2[lane] + s_h[r][lane + 64] * W2[lane + 64];
#pragma unroll
    for (int off = 32; off; off >>= 1) p += __shfl_down(p, off, 64);
    if (lane == 0) {
      int row = r0 + r;
      if (row < n_rows) out[row] = p + b2[0];
    }
  }
}

// ---------------------------------------------------------------------------
// Edge embedding MLP via MFMA. Writes ef0 only (step-0 fused reads ef0 twice).
// ---------------------------------------------------------------------------
__global__ __launch_bounds__(256) void ee_mfma(
    const float* __restrict__ in,
    const ushort* __restrict__ W1p, const float* __restrict__ b1,
    const ushort* __restrict__ W2p, const float* __restrict__ b2,
    ushort* __restrict__ out0)
{
  __shared__ char s_a[64 * 128];
  __shared__ char s_h[64 * 256];
  __shared__ ushort s_o[64 * 128];
  const int t = threadIdx.x;
  const int r0 = blockIdx.x * 64;

  for (int idx = t; idx < 512; idx += 256) {
    int r = idx >> 3, c8 = idx & 7;
    const float* src = in + (size_t)(r0 + r) * 64 + c8 * 8;
    float4 v0 = *(const float4*)src;
    float4 v1 = *(const float4*)(src + 4);
    uint o4[4] = {pk2bf(v0.x, v0.y), pk2bf(v0.z, v0.w),
                  pk2bf(v1.x, v1.y), pk2bf(v1.z, v1.w)};
    *(uint4*)(s_a + ((r * 128 + c8 * 16) ^ ((r & 7) << 4))) = *(uint4*)o4;
  }
  __syncthreads();

  const int lane = t & 63, wave = t >> 6;
  const int r15 = lane & 15, g = lane >> 4;
  const int swz = (r15 & 7) << 4;
  const int arow = wave * 16 + r15;

  f32x4 h1[8];
#pragma unroll
  for (int j = 0; j < 8; ++j) { float bv = b1[j * 16 + r15]; h1[j] = (f32x4){bv, bv, bv, bv}; }
#pragma unroll
  for (int kt = 0; kt < 2; ++kt) {
    short8 a = *(const short8*)(s_a + ((arow * 128 + kt * 64 + g * 16) ^ swz));
    const ushort* wk = W1p + kt * 4096 + r15 * 32 + g * 8;
#pragma unroll
    for (int j = 0; j < 8; ++j) {
      short8 b = *(const short8*)(wk + j * 512);
      h1[j] = __builtin_amdgcn_mfma_f32_16x16x32_bf16(a, b, h1[j], 0, 0, 0);
    }
  }
#pragma unroll
  for (int j = 0; j < 8; ++j)
#pragma unroll
    for (int r = 0; r < 4; ++r) {
      int row = wave * 16 + g * 4 + r;
      int col = j * 16 + r15;
      *(ushort*)(s_h + ((row * 256 + col * 2) ^ ((row & 7) << 4))) = f2bf(fmaxf(h1[j][r], 0.f));
    }
  __syncthreads();

  f32x4 h2[8];
#pragma unroll
  for (int j = 0; j < 8; ++j) { float bv = b2[j * 16 + r15]; h2[j] = (f32x4){bv, bv, bv, bv}; }
#pragma unroll
  for (int kt = 0; kt < 4; ++kt) {
    short8 a = *(const short8*)(s_h + ((arow * 256 + kt * 64 + g * 16) ^ swz));
    const ushort* wk = W2p + kt * 4096 + r15 * 32 + g * 8;
#pragma unroll
    for (int j = 0; j < 8; ++j) {
      short8 b = *(const short8*)(wk + j * 512);
      h2[j] = __builtin_amdgcn_mfma_f32_16x16x32_bf16(a, b, h2[j], 0, 0, 0);
    }
  }
#pragma unroll
  for (int j = 0; j < 8; ++j)
#pragma unroll
    for (int r = 0; r < 4; ++r) {
      int row = wave * 16 + g * 4 + r;
      s_o[row * 128 + j * 16 + r15] = f2bf(fmaxf(h2[j][r], 0.f));
    }
  __syncthreads();
  for (int idx = t; idx < 1024; idx += 256) {
    int r = idx >> 4, c16 = idx & 15;
    uint4 v = *(uint4*)(&s_o[r * 128 + c16 * 8]);
    *(uint4*)(out0 + (size_t)(r0 + r) * 128 + c16 * 8) = v;
  }
}

// ---------------------------------------------------------------------------
// Edge classification head via MFMA.
// ---------------------------------------------------------------------------
__global__ __launch_bounds__(256) void ec_mfma(
    const ushort* __restrict__ feat,
    const ushort* __restrict__ W1p, const float* __restrict__ b1,
    const float* __restrict__ W2, const float* __restrict__ b2,
    float* __restrict__ out)
{
  __shared__ char s_a[64 * 256];
  __shared__ float s_hf[64 * 132];
  const int t = threadIdx.x;
  const int r0 = blockIdx.x * 64;
  for (int idx = t; idx < 1024; idx += 256) {
    int r = idx >> 4, c16 = idx & 15;
    uint4 v = *(const uint4*)(feat + (size_t)(r0 + r) * 128 + c16 * 8);
    *(uint4*)(s_a + ((r * 256 + c16 * 16) ^ ((r & 7) << 4))) = v;
  }
  __syncthreads();
  const int lane = t & 63, wave = t >> 6;
  const int r15 = lane & 15, g = lane >> 4;
  const int swz = (r15 & 7) << 4;
  const int arow = wave * 16 + r15;

  f32x4 h1[8];
#pragma unroll
  for (int j = 0; j < 8; ++j) { float bv = b1[j * 16 + r15]; h1[j] = (f32x4){bv, bv, bv, bv}; }
#pragma unroll
  for (int kt = 0; kt < 4; ++kt) {
    short8 a = *(const short8*)(s_a + ((arow * 256 + kt * 64 + g * 16) ^ swz));
    const ushort* wk = W1p + kt * 4096 + r15 * 32 + g * 8;
#pragma unroll
    for (int j = 0; j < 8; ++j) {
      short8 b = *(const short8*)(wk + j * 512);
      h1[j] = __builtin_amdgcn_mfma_f32_16x16x32_bf16(a, b, h1[j], 0, 0, 0);
    }
  }
#pragma unroll
  for (int j = 0; j < 8; ++j)
#pragma unroll
    for (int r = 0; r < 4; ++r) {
      int row = wave * 16 + g * 4 + r;
      s_hf[row * 132 + j * 16 + r15] = fmaxf(h1[j][r], 0.f);
    }
  __syncthreads();
  {
    int row = t >> 2, q = t & 3;
    float p = 0.f;
#pragma unroll
    for (int c = 0; c < 32; ++c) {
      int col = q * 32 + c;
      p = fmaf(s_hf[row * 132 + col], W2[col], p);
    }
    p += __shfl_down(p, 1, 64);
    p += __shfl_down(p, 2, 64);
    if (q == 0) out[r0 + row] = p + b2[0];
  }
}

// ---------------------------------------------------------------------------
// Per-node precompute: Ppack[n] = [ P_i (512) | P_j (512) | Q (128) ] bf16
// ---------------------------------------------------------------------------
__global__ __launch_bounds__(256) void pre_mfma(
    const ushort* __restrict__ nf0, const ushort* __restrict__ nf,
    const ushort* __restrict__ Wsp, ushort* __restrict__ Ppack)
{
  __shared__ char s_a[64 * 512];   // [64][256] bf16 swizzled
  const int t = threadIdx.x;
  const int r0 = blockIdx.x * 64;
  const int cc = blockIdx.y * 128;

  for (int idx = t; idx < 64 * 32; idx += 256) {
    int r = idx >> 5, c = idx & 31;
    int n = r0 + r; if (n >= N_NODES) n = N_NODES - 1;
    const ushort* base = (c < 16 ? nf0 : nf) + (size_t)n * 128 + (c & 15) * 8;
    *(uint4*)(s_a + ((r * 512 + c * 16) ^ ((r & 7) << 4))) = *(const uint4*)base;
  }
  __syncthreads();

  const int lane = t & 63, wave = t >> 6;
  const int r15 = lane & 15, g = lane >> 4;
  const int swz = (r15 & 7) << 4;

  f32x4 acc[8];
#pragma unroll
  for (int j = 0; j < 8; ++j) acc[j] = (f32x4){0.f, 0.f, 0.f, 0.f};
#pragma unroll
  for (int kt = 0; kt < 8; ++kt) {
    short8 a = *(const short8*)(s_a + (((wave * 16 + r15) * 512 + kt * 64 + g * 16) ^ swz));
    const ushort* wk = Wsp + (size_t)kt * 36864 + (size_t)(cc + r15) * 32 + g * 8;
#pragma unroll
    for (int j = 0; j < 8; ++j) {
      short8 b = *(const short8*)(wk + j * 512);
      acc[j] = __builtin_amdgcn_mfma_f32_16x16x32_bf16(a, b, acc[j], 0, 0, 0);
    }
  }
#pragma unroll
  for (int j = 0; j < 8; ++j)
#pragma unroll
    for (int r = 0; r < 4; ++r) {
      int row = r0 + wave * 16 + g * 4 + r;
      if (row < N_NODES)
        Ppack[(size_t)row * 1152 + cc + j * 16 + r15] = f2bf(acc[j][r]);
    }
}

// ---------------------------------------------------------------------------
// Fused per-step edge kernel (factorized). TE=32 edges/block, 512 thr/8 waves.
// R9: LDS diet (s_q removed; Q read directly from L2/L3-hot Ppack at GEMM3
// init) -> 49.4 KB -> 3 blocks/CU (24 waves/CU) for latency hiding. Grid and
// per-block traffic unchanged (unlike R3's failed TE shrink).
//   stage: A=[ef0|efA] K=256 -> s_a; sP=P_i+P_j -> s_h
//   GEMM1: h = relu(sP + A@W1e + be1)   K=256 -> s_h (own cols, in place)
//   GEMM2: e = relu(h@We2 + be2)        K=512 -> s_a + global ef
//   GEMM3: m = relu(Q + e@W3e + bn1)    K=128 -> atomicAdd agg[i]
// ---------------------------------------------------------------------------
__global__ __launch_bounds__(512, 6) void fused_edge_mfma(
    const ushort* __restrict__ Ppack,
    const ushort* __restrict__ ef0, const ushort* __restrict__ efA,
    ushort* __restrict__ ef,
    const int* __restrict__ ei,
    const ushort* __restrict__ W1ep, const float* __restrict__ be1,
    const ushort* __restrict__ W2p,  const float* __restrict__ be2,
    const ushort* __restrict__ W3ep, const float* __restrict__ bn1,
    float* __restrict__ agg)
{
  __shared__ __align__(16) char s_a[TE * 512];     // 16 KB: A panel, later e
  __shared__ __align__(16) char s_h[TE * 1024];    // 32 KB: sP, then h
  __shared__ int s_i[TE], s_j[TE];

  const int t = threadIdx.x;
  // bijective XCD swizzle: NWG=6250, q=781, rr=2
  const int NWG = N_EDGES / TE;
  const int q = NWG / 8, rr = NWG % 8;
  int xcd = blockIdx.x & 7, bidx = blockIdx.x >> 3;
  int wgid = (xcd < rr ? xcd * (q + 1) : rr * (q + 1) + (xcd - rr) * q) + bidx;
  const int e0 = wgid * TE;

  if (t < TE) s_j[t] = ei[e0 + t];
  else if (t < 2 * TE) s_i[t - TE] = ei[N_EDGES + e0 + (t - TE)];
  __syncthreads();

  // ---- stage A panel [TE][256] = [ef0|efA] (bf16, swizzled) ----
  for (int idx = t; idx < TE * 32; idx += 512) {
    int e = idx >> 5, c = idx & 31;
    const ushort* base = (c < 16 ? ef0 : efA) + (size_t)(e0 + e) * 128 + (c & 15) * 8;
    *(uint4*)(s_a + ((e * 512 + c * 16) ^ ((e & 7) << 4))) = *(const uint4*)base;
  }
  // ---- stage sP = P_i + P_j (f32 add, packed bf16 store) into s_h ----
  for (int idx = t; idx < TE * 64; idx += 512) {
    int e = idx >> 6, c = idx & 63;
    uint4 vi = *(const uint4*)(Ppack + (size_t)s_i[e] * 1152 + c * 8);
    uint4 vj = *(const uint4*)(Ppack + (size_t)s_j[e] * 1152 + 512 + c * 8);
    const ushort* pa = (const ushort*)&vi;
    const ushort* pb = (const ushort*)&vj;
    uint o4[4];
#pragma unroll
    for (int z = 0; z < 4; ++z)
      o4[z] = pk2bf(bf2f(pa[2 * z]) + bf2f(pb[2 * z]),
                    bf2f(pa[2 * z + 1]) + bf2f(pb[2 * z + 1]));
    *(uint4*)(s_h + ((e * 1024 + c * 16) ^ ((e & 7) << 4))) = *(uint4*)o4;
  }
  __syncthreads();

  const int lane = t & 63, wave = t >> 6;
  const int r15 = lane & 15, g = lane >> 4;
  const int swz = (r15 & 7) << 4;
  const int wb = wave * 64, wb2 = wave * 16;

  // ================= GEMM1: K=256, per-wave N=64, init from sP ============
  f32x4 acc1[2][4];
#pragma unroll
  for (int j = 0; j < 4; ++j) {
    float bv = be1[wb + j * 16 + r15];
#pragma unroll
    for (int mt = 0; mt < 2; ++mt)
#pragma unroll
      for (int r = 0; r < 4; ++r) {
        int row = mt * 16 + g * 4 + r;
        int col = wb + j * 16 + r15;
        ushort u = *(const ushort*)(s_h + ((row * 1024 + col * 2) ^ ((row & 7) << 4)));
        acc1[mt][j][r] = bv + bf2f(u);
      }
  }
  {
    const ushort* wkb = W1ep + (size_t)(wb + r15) * 32 + g * 8;
    short8 bc[4], bn[4];
#pragma unroll
    for (int j = 0; j < 4; ++j) bc[j] = *(const short8*)(wkb + j * 512);
    for (int kt = 0; kt < 8; ++kt) {
      short8 a0 = *(const short8*)(s_a + ((r15 * 512 + kt * 64 + g * 16) ^ swz));
      short8 a1 = *(const short8*)(s_a + (((r15 + 16) * 512 + kt * 64 + g * 16) ^ swz));
      const ushort* wnx = wkb + (size_t)(kt + 1) * 16384;  // slack-padded
#pragma unroll
      for (int j = 0; j < 4; ++j) bn[j] = *(const short8*)(wnx + j * 512);
#pragma unroll
      for (int j = 0; j < 4; ++j) {
        acc1[0][j] = __builtin_amdgcn_mfma_f32_16x16x32_bf16(a0, bc[j], acc1[0][j], 0, 0, 0);
        acc1[1][j] = __builtin_amdgcn_mfma_f32_16x16x32_bf16(a1, bc[j], acc1[1][j], 0, 0, 0);
      }
#pragma unroll
      for (int j = 0; j < 4; ++j) bc[j] = bn[j];
    }
  }
  // h write (each wave overwrites only its own columns of s_h)
#pragma unroll
  for (int mt = 0; mt < 2; ++mt)
#pragma unroll
    for (int j = 0; j < 4; ++j)
#pragma unroll
      for (int r = 0; r < 4; ++r) {
        int row = mt * 16 + g * 4 + r;
        int col = wb + j * 16 + r15;
        *(ushort*)(s_h + ((row * 1024 + col * 2) ^ ((row & 7) << 4))) =
            f2bf(fmaxf(acc1[mt][j][r], 0.f));
      }
  __syncthreads();

  // ===== GEMM2: K=512, per-wave N=16, K-split accs + depth-2 B prefetch ===
  f32x4 acc2[2], acc2b[2];
  {
    float bv = be2[wb2 + r15];
    acc2[0] = (f32x4){bv, bv, bv, bv};
    acc2[1] = (f32x4){bv, bv, bv, bv};
    acc2b[0] = (f32x4){0.f, 0.f, 0.f, 0.f};
    acc2b[1] = (f32x4){0.f, 0.f, 0.f, 0.f};
  }
  {
    const ushort* wkb = W2p + (size_t)(wb2 + r15) * 32 + g * 8;
    short8 bA = *(const short8*)(wkb);
    short8 bB = *(const short8*)(wkb + 4096);
    for (int kt2 = 0; kt2 < 8; ++kt2) {
      int ab0 = (2 * kt2) * 64 + g * 16;
      int ab1 = ab0 + 64;
      short8 a0e = *(const short8*)(s_h + ((r15 * 1024 + ab0) ^ swz));
      short8 a1e = *(const short8*)(s_h + (((r15 + 16) * 1024 + ab0) ^ swz));
      short8 a0o = *(const short8*)(s_h + ((r15 * 1024 + ab1) ^ swz));
      short8 a1o = *(const short8*)(s_h + (((r15 + 16) * 1024 + ab1) ^ swz));
      short8 bAn = *(const short8*)(wkb + (size_t)(2 * kt2 + 2) * 4096);  // slack
      short8 bBn = *(const short8*)(wkb + (size_t)(2 * kt2 + 3) * 4096);  // slack
      acc2[0]  = __builtin_amdgcn_mfma_f32_16x16x32_bf16(a0e, bA, acc2[0], 0, 0, 0);
      acc2b[0] = __builtin_amdgcn_mfma_f32_16x16x32_bf16(a0o, bB, acc2b[0], 0, 0, 0);
      acc2[1]  = __builtin_amdgcn_mfma_f32_16x16x32_bf16(a1e, bA, acc2[1], 0, 0, 0);
      acc2b[1] = __builtin_amdgcn_mfma_f32_16x16x32_bf16(a1o, bB, acc2b[1], 0, 0, 0);
      bA = bAn; bB = bBn;
    }
    acc2[0] = acc2[0] + acc2b[0];
    acc2[1] = acc2[1] + acc2b[1];
  }
  // e write into s_a (own cols; s_a dead after GEMM1)
#pragma unroll
  for (int mt = 0; mt < 2; ++mt)
#pragma unroll
    for (int r = 0; r < 4; ++r) {
      int row = mt * 16 + g * 4 + r;
      int col = wb2 + r15;
      *(ushort*)(s_a + ((row * 512 + col * 2) ^ ((row & 7) << 4))) =
          f2bf(fmaxf(acc2[mt][r], 0.f));
    }
  __syncthreads();

  // coalesced e -> global ef (bf16)
  {
    int e = t >> 4, c = t & 15;
    uint4 v = *(const uint4*)(s_a + ((e * 512 + c * 16) ^ ((e & 7) << 4)));
    *(uint4*)(ef + (size_t)(e0 + e) * 128 + c * 8) = v;
  }

  // ====== GEMM3: K=128 (e part), init = bn1 + Q (direct global read) ======
  f32x4 acc3[2];
  {
    float bv = bn1[wb2 + r15];
#pragma unroll
    for (int mt = 0; mt < 2; ++mt)
#pragma unroll
      for (int r = 0; r < 4; ++r) {
        int row = mt * 16 + g * 4 + r;
        acc3[mt][r] = bv +
            bf2f(Ppack[(size_t)s_i[row] * 1152 + 1024 + wb2 + r15]);
      }
  }
  {
    const ushort* w3b = W3ep + (size_t)(wb2 + r15) * 32 + g * 8;
    short8 bq[4];
#pragma unroll
    for (int kk = 0; kk < 4; ++kk) bq[kk] = *(const short8*)(w3b + (size_t)kk * 4096);
#pragma unroll
    for (int kk = 0; kk < 4; ++kk) {
      short8 a0 = *(const short8*)(s_a + ((r15 * 512 + kk * 64 + g * 16) ^ swz));
      short8 a1 = *(const short8*)(s_a + (((r15 + 16) * 512 + kk * 64 + g * 16) ^ swz));
      acc3[0] = __builtin_amdgcn_mfma_f32_16x16x32_bf16(a0, bq[kk], acc3[0], 0, 0, 0);
      acc3[1] = __builtin_amdgcn_mfma_f32_16x16x32_bf16(a1, bq[kk], acc3[1], 0, 0, 0);
    }
  }
  // scatter-add messages to agg (f32 atomics)
#pragma unroll
  for (int mt = 0; mt < 2; ++mt)
#pragma unroll
    for (int r = 0; r < 4; ++r) {
      int row = mt * 16 + g * 4 + r;
      int node = s_i[row];
      atomicAdd(&agg[(size_t)node * 128 + wb2 + r15], fmaxf(acc3[mt][r], 0.f));
    }
}

// ---------------------------------------------------------------------------
extern "C" void kernel_launch(void* const* d_in, const int* in_sizes, int n_in,
                              void* d_out, int out_size, void* d_ws, size_t ws_size,
                              hipStream_t stream) {
  const float* x         = (const float*)d_in[0];
  const float* edge_attr = (const float*)d_in[1];
  const int*   ei        = (const int*)d_in[2];
  const float* Wne1 = (const float*)d_in[3];  const float* bne1 = (const float*)d_in[4];
  const float* Wne2 = (const float*)d_in[5];  const float* bne2 = (const float*)d_in[6];
  const float* Wee1 = (const float*)d_in[7];  const float* bee1 = (const float*)d_in[8];
  const float* Wee2 = (const float*)d_in[9];  const float* bee2 = (const float*)d_in[10];
  const float* We1  = (const float*)d_in[11]; const float* be1  = (const float*)d_in[12];
  const float* We2  = (const float*)d_in[13]; const float* be2  = (const float*)d_in[14];
  const float* Wn1  = (const float*)d_in[15]; const float* bn1  = (const float*)d_in[16];
  const float* Wu   = (const float*)d_in[17]; const float* bu   = (const float*)d_in[18];
  const float* Wnc1 = (const float*)d_in[19]; const float* bnc1 = (const float*)d_in[20];
  const float* Wnc2 = (const float*)d_in[21]; const float* bnc2 = (const float*)d_in[22];
  const float* Wec1 = (const float*)d_in[23]; const float* bec1 = (const float*)d_in[24];
  const float* Wec2 = (const float*)d_in[25]; const float* bec2 = (const float*)d_in[26];

  float* preds_edge = (float*)d_out;         // [E]
  float* preds_node = preds_edge + N_EDGES;  // [N]

  char* w = (char*)d_ws;
  ushort* nf0  = (ushort*)w; w += (size_t)N_NODES * 128 * 2;
  ushort* nf   = (ushort*)w; w += (size_t)N_NODES * 128 * 2;
  ushort* ef0  = (ushort*)w; w += (size_t)N_EDGES * 128 * 2;
  ushort* ef   = (ushort*)w; w += (size_t)N_EDGES * 128 * 2;
  float*  agg  = (float*)w;  w += (size_t)N_NODES * 128 * 4;
  ushort* Ppack = (ushort*)w; w += (size_t)N_NODES * 1152 * 2;   // 23 MB
  ushort* Wsp  = (ushort*)w; w += (size_t)8 * 1152 * 32 * 2;     // 256x1152
  ushort* W1ep = (ushort*)w; w += (size_t)9 * 512 * 32 * 2;      // +1kt slack
  ushort* W2p  = (ushort*)w; w += (size_t)18 * 128 * 32 * 2;     // +2kt slack
  ushort* W3ep = (ushort*)w; w += (size_t)4 * 128 * 32 * 2;
  ushort* Wee1p = (ushort*)w; w += (size_t)64 * 128 * 2;
  ushort* Wee2p = (ushort*)w; w += (size_t)128 * 128 * 2;
  ushort* Wec1p = (ushort*)w; w += (size_t)128 * 128 * 2;
  // total ~138 MB

  permute_all<<<2144, 256, 0, stream>>>(
      We1, We2, Wn1, Wee1, Wee2, Wec1,
      Wsp, W1ep, W2p, W3ep, Wee1p, Wee2p, Wec1p);

  mlp2_kernel<128><<<(N_NODES + 7) / 8, 256, 0, stream>>>(
      x, N_NODES, Wne1, bne1, Wne2, bne2, nf0, nf);
  ee_mfma<<<N_EDGES / 64, 256, 0, stream>>>(
      edge_attr, Wee1p, bee1, Wee2p, bee2, ef0);

  for (int s = 0; s < 2; ++s) {
    pre_mfma<<<dim3((N_NODES + 63) / 64, 9), 256, 0, stream>>>(nf0, nf, Wsp, Ppack);
    hipMemsetAsync(agg, 0, (size_t)N_NODES * 128 * sizeof(float), stream);
    fused_edge_mfma<<<N_EDGES / TE, 512, 0, stream>>>(
        Ppack, ef0, (s == 0 ? ef0 : ef), ef, ei,
        W1ep, be1, W2p, be2, W3ep, bn1, agg);
    mlp1_kernel<<<(N_NODES + 7) / 8, 256, 0, stream>>>(agg, N_NODES, Wu, bu, nf);
  }

  ec_mfma<<<N_EDGES / 64, 256, 0, stream>>>(
      ef, Wec1p, bec1, Wec2, bec2, preds_edge);
  cls_kernel<<<(N_NODES + 7) / 8, 256, 0, stream>>>(
      nf, N_NODES, Wnc1, bnc1, Wnc2, bnc2, preds_node);
}

// Round 11
// 678.880 us; speedup vs baseline: 1.0569x; 1.0569x over previous
//
#include <hip/hip_runtime.h>
#include <hip/hip_bf16.h>

#define N_NODES 10000
#define N_EDGES 200000
#define TE 48   // edges per block in fused edge kernel (3 M-tiles of 16)

typedef __attribute__((ext_vector_type(8))) short short8;
typedef __attribute__((ext_vector_type(4))) float f32x4;

// Native converts: compiler emits v_cvt_pk_bf16_f32 (1 op / 2 floats).
static __device__ __forceinline__ ushort f2bf(float x) {
  union { __hip_bfloat16 h; ushort u; } v;
  v.h = __float2bfloat16(x);
  return v.u;
}
static __device__ __forceinline__ uint pk2bf(float lo, float hi) {
  union { __hip_bfloat162 h; uint u; } v;
  v.h = __float22bfloat162_rn(make_float2(lo, hi));
  return v.u;
}
static __device__ __forceinline__ float bf2f(ushort h) {
  union { uint u; float f; } v; v.u = ((uint)h) << 16;
  return v.f;
}

// ---------------------------------------------------------------------------
// All weight permutes in ONE launch.
// Each job: W[row0+k][ld] f32 -> Wp[kt][n0+n][k32] bf16 (dest Ntot cols).
// ---------------------------------------------------------------------------
__device__ __forceinline__ void permute_job(
    const float* W, ushort* Wp, int o, int K, int N, int ld,
    int row0, int n0, int Ntot)
{
  if (o >= K * N) return;
  int k = o & 31;
  int n = (o >> 5) % N;
  int kt = o / (N * 32);
  Wp[(size_t)kt * Ntot * 32 + (size_t)(n0 + n) * 32 + k] =
      f2bf(W[(size_t)(row0 + kt * 32 + k) * ld + n]);
}

__global__ __launch_bounds__(256) void permute_all(
    const float* __restrict__ We1, const float* __restrict__ We2,
    const float* __restrict__ Wn1, const float* __restrict__ Wee1,
    const float* __restrict__ Wee2, const float* __restrict__ Wec1,
    ushort* __restrict__ Wsp, ushort* __restrict__ W1ep,
    ushort* __restrict__ W2p, ushort* __restrict__ W3ep,
    ushort* __restrict__ Wee1p, ushort* __restrict__ Wee2p,
    ushort* __restrict__ Wec1p)
{
  int b = blockIdx.x, t = threadIdx.x;
  if (b < 512)       permute_job(We1, Wsp,  (b       ) * 256 + t, 256, 512, 512,   0,    0, 1152);
  else if (b < 1024) permute_job(We1, Wsp,  (b - 512 ) * 256 + t, 256, 512, 512, 256,  512, 1152);
  else if (b < 1152) permute_job(Wn1, Wsp,  (b - 1024) * 256 + t, 256, 128, 128,   0, 1024, 1152);
  else if (b < 1664) permute_job(We1, W1ep, (b - 1152) * 256 + t, 256, 512, 512, 512,    0,  512);
  else if (b < 1920) permute_job(We2, W2p,  (b - 1664) * 256 + t, 512, 128, 128,   0,    0,  128);
  else if (b < 1984) permute_job(Wn1, W3ep, (b - 1920) * 256 + t, 128, 128, 128, 256,    0,  128);
  else if (b < 2016) permute_job(Wee1, Wee1p,(b - 1984) * 256 + t,  64, 128, 128,   0,    0,  128);
  else if (b < 2080) permute_job(Wee2, Wee2p,(b - 2016) * 256 + t, 128, 128, 128,   0,    0,  128);
  else               permute_job(Wec1, Wec1p,(b - 2080) * 256 + t, 128, 128, 128,   0,    0,  128);
}

// ---------------------------------------------------------------------------
// Node embedding 2-layer MLP (f32 VALU; only 10K rows): bf16 outputs.
// ---------------------------------------------------------------------------
template <int K1>
__global__ __launch_bounds__(256) void mlp2_kernel(
    const float* __restrict__ in, int n_rows,
    const float* __restrict__ W1, const float* __restrict__ b1,
    const float* __restrict__ W2, const float* __restrict__ b2,
    ushort* __restrict__ out0, ushort* __restrict__ out1)
{
  __shared__ float s_a[8][K1];
  __shared__ float s_h[8][128];
  const int r0 = blockIdx.x * 8;
  const int t = threadIdx.x;

  for (int idx = t; idx < 8 * K1; idx += 256) {
    int r = idx / K1, k = idx - r * K1;
    int row = r0 + r;
    s_a[r][k] = (row < n_rows) ? in[(size_t)row * K1 + k] : 0.f;
  }
  __syncthreads();

  const int c = t & 127;
  const int g = t >> 7;
  float acc[4];
#pragma unroll
  for (int e = 0; e < 4; ++e) acc[e] = b1[c];
  for (int k = 0; k < K1; ++k) {
    float w = W1[(size_t)k * 128 + c];
#pragma unroll
    for (int e = 0; e < 4; ++e) acc[e] = fmaf(s_a[g * 4 + e][k], w, acc[e]);
  }
#pragma unroll
  for (int e = 0; e < 4; ++e) s_h[g * 4 + e][c] = fmaxf(acc[e], 0.f);
  __syncthreads();

#pragma unroll
  for (int e = 0; e < 4; ++e) acc[e] = b2[c];
  for (int k = 0; k < 128; ++k) {
    float w = W2[(size_t)k * 128 + c];
#pragma unroll
    for (int e = 0; e < 4; ++e) acc[e] = fmaf(s_h[g * 4 + e][k], w, acc[e]);
  }
#pragma unroll
  for (int e = 0; e < 4; ++e) {
    int row = r0 + g * 4 + e;
    if (row < n_rows) {
      ushort v = f2bf(fmaxf(acc[e], 0.f));
      out0[(size_t)row * 128 + c] = v;
      if (out1) out1[(size_t)row * 128 + c] = v;
    }
  }
}

// ---------------------------------------------------------------------------
// update MLP: out = relu(agg @ W + b), agg f32, out bf16 (10K rows).
// ---------------------------------------------------------------------------
__global__ __launch_bounds__(256) void mlp1_kernel(
    const float* __restrict__ in, int n_rows,
    const float* __restrict__ W, const float* __restrict__ b,
    ushort* __restrict__ out)
{
  __shared__ float s_a[8][128];
  const int r0 = blockIdx.x * 8;
  const int t = threadIdx.x;
  for (int idx = t; idx < 8 * 128; idx += 256) {
    int r = idx >> 7, k = idx & 127;
    int row = r0 + r;
    s_a[r][k] = (row < n_rows) ? in[(size_t)row * 128 + k] : 0.f;
  }
  __syncthreads();
  const int c = t & 127;
  const int g = t >> 7;
  float acc[4];
#pragma unroll
  for (int e = 0; e < 4; ++e) acc[e] = b[c];
  for (int k = 0; k < 128; ++k) {
    float w = W[(size_t)k * 128 + c];
#pragma unroll
    for (int e = 0; e < 4; ++e) acc[e] = fmaf(s_a[g * 4 + e][k], w, acc[e]);
  }
#pragma unroll
  for (int e = 0; e < 4; ++e) {
    int row = r0 + g * 4 + e;
    if (row < n_rows) out[(size_t)row * 128 + c] = f2bf(fmaxf(acc[e], 0.f));
  }
}

// ---------------------------------------------------------------------------
// Node classification head (10K rows, VALU).
// ---------------------------------------------------------------------------
__global__ __launch_bounds__(256) void cls_kernel(
    const ushort* __restrict__ feat, int n_rows,
    const float* __restrict__ W1, const float* __restrict__ b1,
    const float* __restrict__ W2, const float* __restrict__ b2,
    float* __restrict__ out)
{
  __shared__ float s_a[8][128];
  __shared__ float s_h[8][128];
  const int r0 = blockIdx.x * 8;
  const int t = threadIdx.x;
  for (int idx = t; idx < 8 * 128; idx += 256) {
    int r = idx >> 7, k = idx & 127;
    int row = r0 + r;
    s_a[r][k] = (row < n_rows) ? bf2f(feat[(size_t)row * 128 + k]) : 0.f;
  }
  __syncthreads();
  const int c = t & 127;
  const int g = t >> 7;
  float acc[4];
#pragma unroll
  for (int e = 0; e < 4; ++e) acc[e] = b1[c];
  for (int k = 0; k < 128; ++k) {
    float w = W1[(size_t)k * 128 + c];
#pragma unroll
    for (int e = 0; e < 4; ++e) acc[e] = fmaf(s_a[g * 4 + e][k], w, acc[e]);
  }
#pragma unroll
  for (int e = 0; e < 4; ++e) s_h[g * 4 + e][c] = fmaxf(acc[e], 0.f);
  __syncthreads();

  const int wave = t >> 6, lane = t & 63;
#pragma unroll
  for (int e2 = 0; e2 < 2; ++e2) {
    int r = wave * 2 + e2;
    float p = s_h[r][lane] * W2[lane] + s_h[r][lane + 64] * W2[lane + 64];
#pragma unroll
    for (int off = 32; off; off >>= 1) p += __shfl_down(p, off, 64);
    if (lane == 0) {
      int row = r0 + r;
      if (row < n_rows) out[row] = p + b2[0];
    }
  }
}

// ---------------------------------------------------------------------------
// Edge embedding MLP via MFMA. Writes ef0 only (step-0 fused reads ef0 twice).
// ---------------------------------------------------------------------------
__global__ __launch_bounds__(256) void ee_mfma(
    const float* __restrict__ in,
    const ushort* __restrict__ W1p, const float* __restrict__ b1,
    const ushort* __restrict__ W2p, const float* __restrict__ b2,
    ushort* __restrict__ out0)
{
  __shared__ char s_a[64 * 128];
  __shared__ char s_h[64 * 256];
  __shared__ ushort s_o[64 * 128];
  const int t = threadIdx.x;
  const int r0 = blockIdx.x * 64;

  for (int idx = t; idx < 512; idx += 256) {
    int r = idx >> 3, c8 = idx & 7;
    const float* src = in + (size_t)(r0 + r) * 64 + c8 * 8;
    float4 v0 = *(const float4*)src;
    float4 v1 = *(const float4*)(src + 4);
    uint o4[4] = {pk2bf(v0.x, v0.y), pk2bf(v0.z, v0.w),
                  pk2bf(v1.x, v1.y), pk2bf(v1.z, v1.w)};
    *(uint4*)(s_a + ((r * 128 + c8 * 16) ^ ((r & 7) << 4))) = *(uint4*)o4;
  }
  __syncthreads();

  const int lane = t & 63, wave = t >> 6;
  const int r15 = lane & 15, g = lane >> 4;
  const int swz = (r15 & 7) << 4;
  const int arow = wave * 16 + r15;

  f32x4 h1[8];
#pragma unroll
  for (int j = 0; j < 8; ++j) { float bv = b1[j * 16 + r15]; h1[j] = (f32x4){bv, bv, bv, bv}; }
#pragma unroll
  for (int kt = 0; kt < 2; ++kt) {
    short8 a = *(const short8*)(s_a + ((arow * 128 + kt * 64 + g * 16) ^ swz));
    const ushort* wk = W1p + kt * 4096 + r15 * 32 + g * 8;
#pragma unroll
    for (int j = 0; j < 8; ++j) {
      short8 b = *(const short8*)(wk + j * 512);
      h1[j] = __builtin_amdgcn_mfma_f32_16x16x32_bf16(a, b, h1[j], 0, 0, 0);
    }
  }
#pragma unroll
  for (int j = 0; j < 8; ++j)
#pragma unroll
    for (int r = 0; r < 4; ++r) {
      int row = wave * 16 + g * 4 + r;
      int col = j * 16 + r15;
      *(ushort*)(s_h + ((row * 256 + col * 2) ^ ((row & 7) << 4))) = f2bf(fmaxf(h1[j][r], 0.f));
    }
  __syncthreads();

  f32x4 h2[8];
#pragma unroll
  for (int j = 0; j < 8; ++j) { float bv = b2[j * 16 + r15]; h2[j] = (f32x4){bv, bv, bv, bv}; }
#pragma unroll
  for (int kt = 0; kt < 4; ++kt) {
    short8 a = *(const short8*)(s_h + ((arow * 256 + kt * 64 + g * 16) ^ swz));
    const ushort* wk = W2p + kt * 4096 + r15 * 32 + g * 8;
#pragma unroll
    for (int j = 0; j < 8; ++j) {
      short8 b = *(const short8*)(wk + j * 512);
      h2[j] = __builtin_amdgcn_mfma_f32_16x16x32_bf16(a, b, h2[j], 0, 0, 0);
    }
  }
#pragma unroll
  for (int j = 0; j < 8; ++j)
#pragma unroll
    for (int r = 0; r < 4; ++r) {
      int row = wave * 16 + g * 4 + r;
      s_o[row * 128 + j * 16 + r15] = f2bf(fmaxf(h2[j][r], 0.f));
    }
  __syncthreads();
  for (int idx = t; idx < 1024; idx += 256) {
    int r = idx >> 4, c16 = idx & 15;
    uint4 v = *(uint4*)(&s_o[r * 128 + c16 * 8]);
    *(uint4*)(out0 + (size_t)(r0 + r) * 128 + c16 * 8) = v;
  }
}

// ---------------------------------------------------------------------------
// Edge classification head via MFMA.
// ---------------------------------------------------------------------------
__global__ __launch_bounds__(256) void ec_mfma(
    const ushort* __restrict__ feat,
    const ushort* __restrict__ W1p, const float* __restrict__ b1,
    const float* __restrict__ W2, const float* __restrict__ b2,
    float* __restrict__ out)
{
  __shared__ char s_a[64 * 256];
  __shared__ float s_hf[64 * 132];
  const int t = threadIdx.x;
  const int r0 = blockIdx.x * 64;
  for (int idx = t; idx < 1024; idx += 256) {
    int r = idx >> 4, c16 = idx & 15;
    uint4 v = *(const uint4*)(feat + (size_t)(r0 + r) * 128 + c16 * 8);
    *(uint4*)(s_a + ((r * 256 + c16 * 16) ^ ((r & 7) << 4))) = v;
  }
  __syncthreads();
  const int lane = t & 63, wave = t >> 6;
  const int r15 = lane & 15, g = lane >> 4;
  const int swz = (r15 & 7) << 4;
  const int arow = wave * 16 + r15;

  f32x4 h1[8];
#pragma unroll
  for (int j = 0; j < 8; ++j) { float bv = b1[j * 16 + r15]; h1[j] = (f32x4){bv, bv, bv, bv}; }
#pragma unroll
  for (int kt = 0; kt < 4; ++kt) {
    short8 a = *(const short8*)(s_a + ((arow * 256 + kt * 64 + g * 16) ^ swz));
    const ushort* wk = W1p + kt * 4096 + r15 * 32 + g * 8;
#pragma unroll
    for (int j = 0; j < 8; ++j) {
      short8 b = *(const short8*)(wk + j * 512);
      h1[j] = __builtin_amdgcn_mfma_f32_16x16x32_bf16(a, b, h1[j], 0, 0, 0);
    }
  }
#pragma unroll
  for (int j = 0; j < 8; ++j)
#pragma unroll
    for (int r = 0; r < 4; ++r) {
      int row = wave * 16 + g * 4 + r;
      s_hf[row * 132 + j * 16 + r15] = fmaxf(h1[j][r], 0.f);
    }
  __syncthreads();
  {
    int row = t >> 2, q = t & 3;
    float p = 0.f;
#pragma unroll
    for (int c = 0; c < 32; ++c) {
      int col = q * 32 + c;
      p = fmaf(s_hf[row * 132 + col], W2[col], p);
    }
    p += __shfl_down(p, 1, 64);
    p += __shfl_down(p, 2, 64);
    if (q == 0) out[r0 + row] = p + b2[0];
  }
}

// ---------------------------------------------------------------------------
// Per-node precompute: Ppack[n] = [ P_i (512) | P_j (512) | Q (128) ] bf16
// ---------------------------------------------------------------------------
__global__ __launch_bounds__(256) void pre_mfma(
    const ushort* __restrict__ nf0, const ushort* __restrict__ nf,
    const ushort* __restrict__ Wsp, ushort* __restrict__ Ppack)
{
  __shared__ char s_a[64 * 512];   // [64][256] bf16 swizzled
  const int t = threadIdx.x;
  const int r0 = blockIdx.x * 64;
  const int cc = blockIdx.y * 128;

  for (int idx = t; idx < 64 * 32; idx += 256) {
    int r = idx >> 5, c = idx & 31;
    int n = r0 + r; if (n >= N_NODES) n = N_NODES - 1;
    const ushort* base = (c < 16 ? nf0 : nf) + (size_t)n * 128 + (c & 15) * 8;
    *(uint4*)(s_a + ((r * 512 + c * 16) ^ ((r & 7) << 4))) = *(const uint4*)base;
  }
  __syncthreads();

  const int lane = t & 63, wave = t >> 6;
  const int r15 = lane & 15, g = lane >> 4;
  const int swz = (r15 & 7) << 4;

  f32x4 acc[8];
#pragma unroll
  for (int j = 0; j < 8; ++j) acc[j] = (f32x4){0.f, 0.f, 0.f, 0.f};
#pragma unroll
  for (int kt = 0; kt < 8; ++kt) {
    short8 a = *(const short8*)(s_a + (((wave * 16 + r15) * 512 + kt * 64 + g * 16) ^ swz));
    const ushort* wk = Wsp + (size_t)kt * 36864 + (size_t)(cc + r15) * 32 + g * 8;
#pragma unroll
    for (int j = 0; j < 8; ++j) {
      short8 b = *(const short8*)(wk + j * 512);
      acc[j] = __builtin_amdgcn_mfma_f32_16x16x32_bf16(a, b, acc[j], 0, 0, 0);
    }
  }
#pragma unroll
  for (int j = 0; j < 8; ++j)
#pragma unroll
    for (int r = 0; r < 4; ++r) {
      int row = r0 + wave * 16 + g * 4 + r;
      if (row < N_NODES)
        Ppack[(size_t)row * 1152 + cc + j * 16 + r15] = f2bf(acc[j][r]);
    }
}

// ---------------------------------------------------------------------------
// Fused per-step edge kernel (factorized). R10: TE=48 (3 M-tiles) at the
// SAME 2 blocks/CU (LDS 72.4 KB) — 1.5x weight amortization per block and
// 1.5x MFMA per kt vs R8's TE=32; grid 6250->4167. Occupancy deliberately
// NOT raised (R3/R9: 3 blocks/CU thrashes L2). Q read direct from L2-hot
// Ppack at GEMM3 init (frees the 13 KB s_q that TE=48 couldn't afford).
//   stage: A=[ef0|efA] K=256 -> s_a; sP=P_i+P_j -> s_h
//   GEMM1: h = relu(sP + A@W1e + be1)   K=256 -> s_h (own cols, in place)
//   GEMM2: e = relu(h@We2 + be2)        K=512 -> s_a + global ef
//   GEMM3: m = relu(Q + e@W3e + bn1)    K=128 -> atomicAdd agg[i]
// ---------------------------------------------------------------------------
__global__ __launch_bounds__(512, 4) void fused_edge_mfma(
    const ushort* __restrict__ Ppack,
    const ushort* __restrict__ ef0, const ushort* __restrict__ efA,
    ushort* __restrict__ ef,
    const int* __restrict__ ei,
    const ushort* __restrict__ W1ep, const float* __restrict__ be1,
    const ushort* __restrict__ W2p,  const float* __restrict__ be2,
    const ushort* __restrict__ W3ep, const float* __restrict__ bn1,
    float* __restrict__ agg)
{
  __shared__ __align__(16) char s_a[TE * 512];     // 24 KB: A panel, later e
  __shared__ __align__(16) char s_h[TE * 1024];    // 48 KB: sP, then h
  __shared__ int s_i[TE], s_j[TE];

  const int t = threadIdx.x;
  // bijective XCD swizzle: NWG=4167, q=520, rr=7 (verified bijective)
  const int NWG = (N_EDGES + TE - 1) / TE;
  const int q = NWG / 8, rr = NWG % 8;
  int xcd = blockIdx.x & 7, bidx = blockIdx.x >> 3;
  int wgid = (xcd < rr ? xcd * (q + 1) : rr * (q + 1) + (xcd - rr) * q) + bidx;
  const int e0 = wgid * TE;

  if (t < TE) {
    int e = e0 + t; if (e >= N_EDGES) e = N_EDGES - 1;
    s_j[t] = ei[e];
  } else if (t < 2 * TE) {
    int e = e0 + t - TE; if (e >= N_EDGES) e = N_EDGES - 1;
    s_i[t - TE] = ei[N_EDGES + e];
  }
  __syncthreads();

  // ---- stage A panel [TE][256] = [ef0|efA] (bf16, swizzled) ----
  for (int idx = t; idx < TE * 32; idx += 512) {
    int e = idx >> 5, c = idx & 31;
    int er = e0 + e; if (er >= N_EDGES) er = N_EDGES - 1;
    const ushort* base = (c < 16 ? ef0 : efA) + (size_t)er * 128 + (c & 15) * 8;
    *(uint4*)(s_a + ((e * 512 + c * 16) ^ ((e & 7) << 4))) = *(const uint4*)base;
  }
  // ---- stage sP = P_i + P_j (f32 add, packed bf16 store) into s_h ----
  for (int idx = t; idx < TE * 64; idx += 512) {
    int e = idx >> 6, c = idx & 63;
    uint4 vi = *(const uint4*)(Ppack + (size_t)s_i[e] * 1152 + c * 8);
    uint4 vj = *(const uint4*)(Ppack + (size_t)s_j[e] * 1152 + 512 + c * 8);
    const ushort* pa = (const ushort*)&vi;
    const ushort* pb = (const ushort*)&vj;
    uint o4[4];
#pragma unroll
    for (int z = 0; z < 4; ++z)
      o4[z] = pk2bf(bf2f(pa[2 * z]) + bf2f(pb[2 * z]),
                    bf2f(pa[2 * z + 1]) + bf2f(pb[2 * z + 1]));
    *(uint4*)(s_h + ((e * 1024 + c * 16) ^ ((e & 7) << 4))) = *(uint4*)o4;
  }
  __syncthreads();

  const int lane = t & 63, wave = t >> 6;
  const int r15 = lane & 15, g = lane >> 4;
  const int swz = (r15 & 7) << 4;
  const int wb = wave * 64, wb2 = wave * 16;

  // ================= GEMM1: K=256, per-wave N=64, init from sP ============
  f32x4 acc1[3][4];
#pragma unroll
  for (int j = 0; j < 4; ++j) {
    float bv = be1[wb + j * 16 + r15];
#pragma unroll
    for (int mt = 0; mt < 3; ++mt)
#pragma unroll
      for (int r = 0; r < 4; ++r) {
        int row = mt * 16 + g * 4 + r;
        int col = wb + j * 16 + r15;
        ushort u = *(const ushort*)(s_h + ((row * 1024 + col * 2) ^ ((row & 7) << 4)));
        acc1[mt][j][r] = bv + bf2f(u);
      }
  }
  {
    const ushort* wkb = W1ep + (size_t)(wb + r15) * 32 + g * 8;
    short8 bc[4], bn[4];
#pragma unroll
    for (int j = 0; j < 4; ++j) bc[j] = *(const short8*)(wkb + j * 512);
    for (int kt = 0; kt < 8; ++kt) {
      short8 a0 = *(const short8*)(s_a + (((r15     ) * 512 + kt * 64 + g * 16) ^ swz));
      short8 a1 = *(const short8*)(s_a + (((r15 + 16) * 512 + kt * 64 + g * 16) ^ swz));
      short8 a2 = *(const short8*)(s_a + (((r15 + 32) * 512 + kt * 64 + g * 16) ^ swz));
      const ushort* wnx = wkb + (size_t)(kt + 1) * 16384;  // slack-padded
#pragma unroll
      for (int j = 0; j < 4; ++j) bn[j] = *(const short8*)(wnx + j * 512);
#pragma unroll
      for (int j = 0; j < 4; ++j) {
        acc1[0][j] = __builtin_amdgcn_mfma_f32_16x16x32_bf16(a0, bc[j], acc1[0][j], 0, 0, 0);
        acc1[1][j] = __builtin_amdgcn_mfma_f32_16x16x32_bf16(a1, bc[j], acc1[1][j], 0, 0, 0);
        acc1[2][j] = __builtin_amdgcn_mfma_f32_16x16x32_bf16(a2, bc[j], acc1[2][j], 0, 0, 0);
      }
#pragma unroll
      for (int j = 0; j < 4; ++j) bc[j] = bn[j];
    }
  }
  // h write (each wave overwrites only its own columns of s_h)
#pragma unroll
  for (int mt = 0; mt < 3; ++mt)
#pragma unroll
    for (int j = 0; j < 4; ++j)
#pragma unroll
      for (int r = 0; r < 4; ++r) {
        int row = mt * 16 + g * 4 + r;
        int col = wb + j * 16 + r15;
        *(ushort*)(s_h + ((row * 1024 + col * 2) ^ ((row & 7) << 4))) =
            f2bf(fmaxf(acc1[mt][j][r], 0.f));
      }
  __syncthreads();

  // ===== GEMM2: K=512, per-wave N=16, K-split accs + depth-2 B prefetch ===
  f32x4 acc2[3], acc2b[3];
  {
    float bv = be2[wb2 + r15];
#pragma unroll
    for (int mt = 0; mt < 3; ++mt) {
      acc2[mt] = (f32x4){bv, bv, bv, bv};
      acc2b[mt] = (f32x4){0.f, 0.f, 0.f, 0.f};
    }
  }
  {
    const ushort* wkb = W2p + (size_t)(wb2 + r15) * 32 + g * 8;
    short8 bA = *(const short8*)(wkb);
    short8 bB = *(const short8*)(wkb + 4096);
    for (int kt2 = 0; kt2 < 8; ++kt2) {
      int ab0 = (2 * kt2) * 64 + g * 16;
      int ab1 = ab0 + 64;
      short8 a0e = *(const short8*)(s_h + (((r15     ) * 1024 + ab0) ^ swz));
      short8 a1e = *(const short8*)(s_h + (((r15 + 16) * 1024 + ab0) ^ swz));
      short8 a2e = *(const short8*)(s_h + (((r15 + 32) * 1024 + ab0) ^ swz));
      short8 a0o = *(const short8*)(s_h + (((r15     ) * 1024 + ab1) ^ swz));
      short8 a1o = *(const short8*)(s_h + (((r15 + 16) * 1024 + ab1) ^ swz));
      short8 a2o = *(const short8*)(s_h + (((r15 + 32) * 1024 + ab1) ^ swz));
      short8 bAn = *(const short8*)(wkb + (size_t)(2 * kt2 + 2) * 4096);  // slack
      short8 bBn = *(const short8*)(wkb + (size_t)(2 * kt2 + 3) * 4096);  // slack
      acc2[0]  = __builtin_amdgcn_mfma_f32_16x16x32_bf16(a0e, bA, acc2[0], 0, 0, 0);
      acc2b[0] = __builtin_amdgcn_mfma_f32_16x16x32_bf16(a0o, bB, acc2b[0], 0, 0, 0);
      acc2[1]  = __builtin_amdgcn_mfma_f32_16x16x32_bf16(a1e, bA, acc2[1], 0, 0, 0);
      acc2b[1] = __builtin_amdgcn_mfma_f32_16x16x32_bf16(a1o, bB, acc2b[1], 0, 0, 0);
      acc2[2]  = __builtin_amdgcn_mfma_f32_16x16x32_bf16(a2e, bA, acc2[2], 0, 0, 0);
      acc2b[2] = __builtin_amdgcn_mfma_f32_16x16x32_bf16(a2o, bB, acc2b[2], 0, 0, 0);
      bA = bAn; bB = bBn;
    }
#pragma unroll
    for (int mt = 0; mt < 3; ++mt) acc2[mt] = acc2[mt] + acc2b[mt];
  }
  // e write into s_a (own cols; s_a dead after GEMM1)
#pragma unroll
  for (int mt = 0; mt < 3; ++mt)
#pragma unroll
    for (int r = 0; r < 4; ++r) {
      int row = mt * 16 + g * 4 + r;
      int col = wb2 + r15;
      *(ushort*)(s_a + ((row * 512 + col * 2) ^ ((row & 7) << 4))) =
          f2bf(fmaxf(acc2[mt][r], 0.f));
    }
  __syncthreads();

  // coalesced e -> global ef (bf16)
  for (int idx = t; idx < TE * 16; idx += 512) {
    int e = idx >> 4, c = idx & 15;
    if (e0 + e < N_EDGES) {
      uint4 v = *(const uint4*)(s_a + ((e * 512 + c * 16) ^ ((e & 7) << 4)));
      *(uint4*)(ef + (size_t)(e0 + e) * 128 + c * 8) = v;
    }
  }

  // ====== GEMM3: K=128 (e part), init = bn1 + Q (direct global read) ======
  f32x4 acc3[3];
  {
    float bv = bn1[wb2 + r15];
#pragma unroll
    for (int mt = 0; mt < 3; ++mt)
#pragma unroll
      for (int r = 0; r < 4; ++r) {
        int row = mt * 16 + g * 4 + r;
        acc3[mt][r] = bv +
            bf2f(Ppack[(size_t)s_i[row] * 1152 + 1024 + wb2 + r15]);
      }
  }
  {
    const ushort* w3b = W3ep + (size_t)(wb2 + r15) * 32 + g * 8;
    short8 bq[4];
#pragma unroll
    for (int kk = 0; kk < 4; ++kk) bq[kk] = *(const short8*)(w3b + (size_t)kk * 4096);
#pragma unroll
    for (int kk = 0; kk < 4; ++kk) {
      short8 a0 = *(const short8*)(s_a + (((r15     ) * 512 + kk * 64 + g * 16) ^ swz));
      short8 a1 = *(const short8*)(s_a + (((r15 + 16) * 512 + kk * 64 + g * 16) ^ swz));
      short8 a2 = *(const short8*)(s_a + (((r15 + 32) * 512 + kk * 64 + g * 16) ^ swz));
      acc3[0] = __builtin_amdgcn_mfma_f32_16x16x32_bf16(a0, bq[kk], acc3[0], 0, 0, 0);
      acc3[1] = __builtin_amdgcn_mfma_f32_16x16x32_bf16(a1, bq[kk], acc3[1], 0, 0, 0);
      acc3[2] = __builtin_amdgcn_mfma_f32_16x16x32_bf16(a2, bq[kk], acc3[2], 0, 0, 0);
    }
  }
  // scatter-add messages to agg (f32 atomics), edge-tail guarded
#pragma unroll
  for (int mt = 0; mt < 3; ++mt)
#pragma unroll
    for (int r = 0; r < 4; ++r) {
      int row = mt * 16 + g * 4 + r;
      if (e0 + row < N_EDGES) {
        int node = s_i[row];
        atomicAdd(&agg[(size_t)node * 128 + wb2 + r15], fmaxf(acc3[mt][r], 0.f));
      }
    }
}

// ---------------------------------------------------------------------------
extern "C" void kernel_launch(void* const* d_in, const int* in_sizes, int n_in,
                              void* d_out, int out_size, void* d_ws, size_t ws_size,
                              hipStream_t stream) {
  const float* x         = (const float*)d_in[0];
  const float* edge_attr = (const float*)d_in[1];
  const int*   ei        = (const int*)d_in[2];
  const float* Wne1 = (const float*)d_in[3];  const float* bne1 = (const float*)d_in[4];
  const float* Wne2 = (const float*)d_in[5];  const float* bne2 = (const float*)d_in[6];
  const float* Wee1 = (const float*)d_in[7];  const float* bee1 = (const float*)d_in[8];
  const float* Wee2 = (const float*)d_in[9];  const float* bee2 = (const float*)d_in[10];
  const float* We1  = (const float*)d_in[11]; const float* be1  = (const float*)d_in[12];
  const float* We2  = (const float*)d_in[13]; const float* be2  = (const float*)d_in[14];
  const float* Wn1  = (const float*)d_in[15]; const float* bn1  = (const float*)d_in[16];
  const float* Wu   = (const float*)d_in[17]; const float* bu   = (const float*)d_in[18];
  const float* Wnc1 = (const float*)d_in[19]; const float* bnc1 = (const float*)d_in[20];
  const float* Wnc2 = (const float*)d_in[21]; const float* bnc2 = (const float*)d_in[22];
  const float* Wec1 = (const float*)d_in[23]; const float* bec1 = (const float*)d_in[24];
  const float* Wec2 = (const float*)d_in[25]; const float* bec2 = (const float*)d_in[26];

  float* preds_edge = (float*)d_out;         // [E]
  float* preds_node = preds_edge + N_EDGES;  // [N]

  char* w = (char*)d_ws;
  ushort* nf0  = (ushort*)w; w += (size_t)N_NODES * 128 * 2;
  ushort* nf   = (ushort*)w; w += (size_t)N_NODES * 128 * 2;
  ushort* ef0  = (ushort*)w; w += (size_t)N_EDGES * 128 * 2;
  ushort* ef   = (ushort*)w; w += (size_t)N_EDGES * 128 * 2;
  float*  agg  = (float*)w;  w += (size_t)N_NODES * 128 * 4;
  ushort* Ppack = (ushort*)w; w += (size_t)N_NODES * 1152 * 2;   // 23 MB
  ushort* Wsp  = (ushort*)w; w += (size_t)8 * 1152 * 32 * 2;     // 256x1152
  ushort* W1ep = (ushort*)w; w += (size_t)9 * 512 * 32 * 2;      // +1kt slack
  ushort* W2p  = (ushort*)w; w += (size_t)18 * 128 * 32 * 2;     // +2kt slack
  ushort* W3ep = (ushort*)w; w += (size_t)4 * 128 * 32 * 2;
  ushort* Wee1p = (ushort*)w; w += (size_t)64 * 128 * 2;
  ushort* Wee2p = (ushort*)w; w += (size_t)128 * 128 * 2;
  ushort* Wec1p = (ushort*)w; w += (size_t)128 * 128 * 2;
  // total ~138 MB

  permute_all<<<2144, 256, 0, stream>>>(
      We1, We2, Wn1, Wee1, Wee2, Wec1,
      Wsp, W1ep, W2p, W3ep, Wee1p, Wee2p, Wec1p);

  mlp2_kernel<128><<<(N_NODES + 7) / 8, 256, 0, stream>>>(
      x, N_NODES, Wne1, bne1, Wne2, bne2, nf0, nf);
  ee_mfma<<<N_EDGES / 64, 256, 0, stream>>>(
      edge_attr, Wee1p, bee1, Wee2p, bee2, ef0);

  for (int s = 0; s < 2; ++s) {
    pre_mfma<<<dim3((N_NODES + 63) / 64, 9), 256, 0, stream>>>(nf0, nf, Wsp, Ppack);
    hipMemsetAsync(agg, 0, (size_t)N_NODES * 128 * sizeof(float), stream);
    fused_edge_mfma<<<(N_EDGES + TE - 1) / TE, 512, 0, stream>>>(
        Ppack, ef0, (s == 0 ? ef0 : ef), ef, ei,
        W1ep, be1, W2p, be2, W3ep, bn1, agg);
    mlp1_kernel<<<(N_NODES + 7) / 8, 256, 0, stream>>>(agg, N_NODES, Wu, bu, nf);
  }

  ec_mfma<<<N_EDGES / 64, 256, 0, stream>>>(
      ef, Wec1p, bec1, Wec2, bec2, preds_edge);
  cls_kernel<<<(N_NODES + 7) / 8, 256, 0, stream>>>(
      nf, N_NODES, Wnc1, bnc1, Wnc2, bnc2, preds_node);
}

// Round 12
// 652.587 us; speedup vs baseline: 1.0995x; 1.0403x over previous
//
#include <hip/hip_runtime.h>
#include <hip/hip_bf16.h>

#define N_NODES 10000
#define N_EDGES 200000
#define TE 32   // edges per block in fused edge kernel (2 M-tiles of 16)

typedef __attribute__((ext_vector_type(8))) short short8;
typedef __attribute__((ext_vector_type(4))) float f32x4;

// Native converts: compiler emits v_cvt_pk_bf16_f32 (1 op / 2 floats).
static __device__ __forceinline__ ushort f2bf(float x) {
  union { __hip_bfloat16 h; ushort u; } v;
  v.h = __float2bfloat16(x);
  return v.u;
}
static __device__ __forceinline__ uint pk2bf(float lo, float hi) {
  union { __hip_bfloat162 h; uint u; } v;
  v.h = __float22bfloat162_rn(make_float2(lo, hi));
  return v.u;
}
static __device__ __forceinline__ float bf2f(ushort h) {
  union { uint u; float f; } v; v.u = ((uint)h) << 16;
  return v.f;
}

// ---------------------------------------------------------------------------
// All weight permutes in ONE launch.
// Each job: W[row0+k][ld] f32 -> Wp[kt][n0+n][k32] bf16 (dest Ntot cols).
// ---------------------------------------------------------------------------
__device__ __forceinline__ void permute_job(
    const float* W, ushort* Wp, int o, int K, int N, int ld,
    int row0, int n0, int Ntot)
{
  if (o >= K * N) return;
  int k = o & 31;
  int n = (o >> 5) % N;
  int kt = o / (N * 32);
  Wp[(size_t)kt * Ntot * 32 + (size_t)(n0 + n) * 32 + k] =
      f2bf(W[(size_t)(row0 + kt * 32 + k) * ld + n]);
}

__global__ __launch_bounds__(256) void permute_all(
    const float* __restrict__ We1, const float* __restrict__ We2,
    const float* __restrict__ Wn1, const float* __restrict__ Wee1,
    const float* __restrict__ Wee2, const float* __restrict__ Wec1,
    ushort* __restrict__ Wsp, ushort* __restrict__ W1ep,
    ushort* __restrict__ W2p, ushort* __restrict__ W3ep,
    ushort* __restrict__ Wee1p, ushort* __restrict__ Wee2p,
    ushort* __restrict__ Wec1p)
{
  int b = blockIdx.x, t = threadIdx.x;
  if (b < 512)       permute_job(We1, Wsp,  (b       ) * 256 + t, 256, 512, 512,   0,    0, 1152);
  else if (b < 1024) permute_job(We1, Wsp,  (b - 512 ) * 256 + t, 256, 512, 512, 256,  512, 1152);
  else if (b < 1152) permute_job(Wn1, Wsp,  (b - 1024) * 256 + t, 256, 128, 128,   0, 1024, 1152);
  else if (b < 1664) permute_job(We1, W1ep, (b - 1152) * 256 + t, 256, 512, 512, 512,    0,  512);
  else if (b < 1920) permute_job(We2, W2p,  (b - 1664) * 256 + t, 512, 128, 128,   0,    0,  128);
  else if (b < 1984) permute_job(Wn1, W3ep, (b - 1920) * 256 + t, 128, 128, 128, 256,    0,  128);
  else if (b < 2016) permute_job(Wee1, Wee1p,(b - 1984) * 256 + t,  64, 128, 128,   0,    0,  128);
  else if (b < 2080) permute_job(Wee2, Wee2p,(b - 2016) * 256 + t, 128, 128, 128,   0,    0,  128);
  else               permute_job(Wec1, Wec1p,(b - 2080) * 256 + t, 128, 128, 128,   0,    0,  128);
}

// ---------------------------------------------------------------------------
// update MLP: out = relu(agg @ W + b), agg f32, out bf16 (10K rows).
// ---------------------------------------------------------------------------
__global__ __launch_bounds__(256) void mlp1_kernel(
    const float* __restrict__ in, int n_rows,
    const float* __restrict__ W, const float* __restrict__ b,
    ushort* __restrict__ out)
{
  __shared__ float s_a[8][128];
  const int r0 = blockIdx.x * 8;
  const int t = threadIdx.x;
  for (int idx = t; idx < 8 * 128; idx += 256) {
    int r = idx >> 7, k = idx & 127;
    int row = r0 + r;
    s_a[r][k] = (row < n_rows) ? in[(size_t)row * 128 + k] : 0.f;
  }
  __syncthreads();
  const int c = t & 127;
  const int g = t >> 7;
  float acc[4];
#pragma unroll
  for (int e = 0; e < 4; ++e) acc[e] = b[c];
  for (int k = 0; k < 128; ++k) {
    float w = W[(size_t)k * 128 + c];
#pragma unroll
    for (int e = 0; e < 4; ++e) acc[e] = fmaf(s_a[g * 4 + e][k], w, acc[e]);
  }
#pragma unroll
  for (int e = 0; e < 4; ++e) {
    int row = r0 + g * 4 + e;
    if (row < n_rows) out[(size_t)row * 128 + c] = f2bf(fmaxf(acc[e], 0.f));
  }
}

// ---------------------------------------------------------------------------
// embed_all: blocks [0,1250) node-embed MLP (f32 VALU); [1250,4375) edge-
// embed MLP via MFMA (writes ef0 only). Independent work, one launch.
// ---------------------------------------------------------------------------
__global__ __launch_bounds__(256) void embed_all(
    const float* __restrict__ x,
    const float* __restrict__ Wne1, const float* __restrict__ bne1,
    const float* __restrict__ Wne2, const float* __restrict__ bne2,
    const float* __restrict__ edge_attr,
    const ushort* __restrict__ Wee1p, const float* __restrict__ bee1,
    const ushort* __restrict__ Wee2p, const float* __restrict__ bee2,
    ushort* __restrict__ nf0, ushort* __restrict__ nf,
    ushort* __restrict__ ef0)
{
  __shared__ __align__(16) char smem[40960];
  const int t = threadIdx.x;

  if (blockIdx.x < 1250) {
    // ---------------- node embedding: 8 rows, 128->128->128 ----------------
    float* s_a = (float*)smem;              // [8][128]
    float* s_h = (float*)(smem + 4096);     // [8][128]
    const int r0 = blockIdx.x * 8;
    for (int idx = t; idx < 1024; idx += 256) {
      int r = idx >> 7, k = idx & 127;
      s_a[r * 128 + k] = x[(size_t)(r0 + r) * 128 + k];
    }
    __syncthreads();
    const int c = t & 127, g = t >> 7;
    float acc[4];
#pragma unroll
    for (int e = 0; e < 4; ++e) acc[e] = bne1[c];
    for (int k = 0; k < 128; ++k) {
      float w = Wne1[(size_t)k * 128 + c];
#pragma unroll
      for (int e = 0; e < 4; ++e) acc[e] = fmaf(s_a[(g * 4 + e) * 128 + k], w, acc[e]);
    }
#pragma unroll
    for (int e = 0; e < 4; ++e) s_h[(g * 4 + e) * 128 + c] = fmaxf(acc[e], 0.f);
    __syncthreads();
#pragma unroll
    for (int e = 0; e < 4; ++e) acc[e] = bne2[c];
    for (int k = 0; k < 128; ++k) {
      float w = Wne2[(size_t)k * 128 + c];
#pragma unroll
      for (int e = 0; e < 4; ++e) acc[e] = fmaf(s_h[(g * 4 + e) * 128 + k], w, acc[e]);
    }
#pragma unroll
    for (int e = 0; e < 4; ++e) {
      int row = r0 + g * 4 + e;
      ushort v = f2bf(fmaxf(acc[e], 0.f));
      nf0[(size_t)row * 128 + c] = v;
      nf[(size_t)row * 128 + c] = v;
    }
    return;
  }

  // ---------------- edge embedding: 64 rows, 64->128->128 (MFMA) ----------
  char* s_a = smem;                       // 8 KB  [64][64] bf16 swz
  char* s_h = smem + 8192;                // 16 KB [64][128] bf16 swz
  ushort* s_o = (ushort*)(smem + 24576);  // 16 KB [64][128] row-major
  const int r0 = (blockIdx.x - 1250) * 64;

  for (int idx = t; idx < 512; idx += 256) {
    int r = idx >> 3, c8 = idx & 7;
    const float* src = edge_attr + (size_t)(r0 + r) * 64 + c8 * 8;
    float4 v0 = *(const float4*)src;
    float4 v1 = *(const float4*)(src + 4);
    uint o4[4] = {pk2bf(v0.x, v0.y), pk2bf(v0.z, v0.w),
                  pk2bf(v1.x, v1.y), pk2bf(v1.z, v1.w)};
    *(uint4*)(s_a + ((r * 128 + c8 * 16) ^ ((r & 7) << 4))) = *(uint4*)o4;
  }
  __syncthreads();

  const int lane = t & 63, wave = t >> 6;
  const int r15 = lane & 15, g = lane >> 4;
  const int swz = (r15 & 7) << 4;
  const int arow = wave * 16 + r15;

  f32x4 h1[8];
#pragma unroll
  for (int j = 0; j < 8; ++j) { float bv = bee1[j * 16 + r15]; h1[j] = (f32x4){bv, bv, bv, bv}; }
#pragma unroll
  for (int kt = 0; kt < 2; ++kt) {
    short8 a = *(const short8*)(s_a + ((arow * 128 + kt * 64 + g * 16) ^ swz));
    const ushort* wk = Wee1p + kt * 4096 + r15 * 32 + g * 8;
#pragma unroll
    for (int j = 0; j < 8; ++j) {
      short8 b = *(const short8*)(wk + j * 512);
      h1[j] = __builtin_amdgcn_mfma_f32_16x16x32_bf16(a, b, h1[j], 0, 0, 0);
    }
  }
#pragma unroll
  for (int j = 0; j < 8; ++j)
#pragma unroll
    for (int r = 0; r < 4; ++r) {
      int row = wave * 16 + g * 4 + r;
      int col = j * 16 + r15;
      *(ushort*)(s_h + ((row * 256 + col * 2) ^ ((row & 7) << 4))) = f2bf(fmaxf(h1[j][r], 0.f));
    }
  __syncthreads();

  f32x4 h2[8];
#pragma unroll
  for (int j = 0; j < 8; ++j) { float bv = bee2[j * 16 + r15]; h2[j] = (f32x4){bv, bv, bv, bv}; }
#pragma unroll
  for (int kt = 0; kt < 4; ++kt) {
    short8 a = *(const short8*)(s_h + ((arow * 256 + kt * 64 + g * 16) ^ swz));
    const ushort* wk = Wee2p + kt * 4096 + r15 * 32 + g * 8;
#pragma unroll
    for (int j = 0; j < 8; ++j) {
      short8 b = *(const short8*)(wk + j * 512);
      h2[j] = __builtin_amdgcn_mfma_f32_16x16x32_bf16(a, b, h2[j], 0, 0, 0);
    }
  }
#pragma unroll
  for (int j = 0; j < 8; ++j)
#pragma unroll
    for (int r = 0; r < 4; ++r) {
      int row = wave * 16 + g * 4 + r;
      s_o[row * 128 + j * 16 + r15] = f2bf(fmaxf(h2[j][r], 0.f));
    }
  __syncthreads();
  for (int idx = t; idx < 1024; idx += 256) {
    int r = idx >> 4, c16 = idx & 15;
    uint4 v = *(uint4*)(&s_o[r * 128 + c16 * 8]);
    *(uint4*)(ef0 + (size_t)(r0 + r) * 128 + c16 * 8) = v;
  }
}

// ---------------------------------------------------------------------------
// head_all: blocks [0,3125) edge-cls head (MFMA); [3125,4375) node-cls (VALU).
// ---------------------------------------------------------------------------
__global__ __launch_bounds__(256) void head_all(
    const ushort* __restrict__ ef,
    const ushort* __restrict__ Wec1p, const float* __restrict__ bec1,
    const float* __restrict__ Wec2, const float* __restrict__ bec2,
    const ushort* __restrict__ nf,
    const float* __restrict__ Wnc1, const float* __restrict__ bnc1,
    const float* __restrict__ Wnc2, const float* __restrict__ bnc2,
    float* __restrict__ preds_edge, float* __restrict__ preds_node)
{
  __shared__ __align__(16) char smem[50176];
  const int t = threadIdx.x;

  if (blockIdx.x < 3125) {
    // ---------------- edge classification head (MFMA) ----------------------
    char* s_a = smem;                        // 16 KB [64][128] bf16 swz
    float* s_hf = (float*)(smem + 16384);    // 33.8 KB [64][132] f32
    const int r0 = blockIdx.x * 64;
    for (int idx = t; idx < 1024; idx += 256) {
      int r = idx >> 4, c16 = idx & 15;
      uint4 v = *(const uint4*)(ef + (size_t)(r0 + r) * 128 + c16 * 8);
      *(uint4*)(s_a + ((r * 256 + c16 * 16) ^ ((r & 7) << 4))) = v;
    }
    __syncthreads();
    const int lane = t & 63, wave = t >> 6;
    const int r15 = lane & 15, g = lane >> 4;
    const int swz = (r15 & 7) << 4;
    const int arow = wave * 16 + r15;

    f32x4 h1[8];
#pragma unroll
    for (int j = 0; j < 8; ++j) { float bv = bec1[j * 16 + r15]; h1[j] = (f32x4){bv, bv, bv, bv}; }
#pragma unroll
    for (int kt = 0; kt < 4; ++kt) {
      short8 a = *(const short8*)(s_a + ((arow * 256 + kt * 64 + g * 16) ^ swz));
      const ushort* wk = Wec1p + kt * 4096 + r15 * 32 + g * 8;
#pragma unroll
      for (int j = 0; j < 8; ++j) {
        short8 b = *(const short8*)(wk + j * 512);
        h1[j] = __builtin_amdgcn_mfma_f32_16x16x32_bf16(a, b, h1[j], 0, 0, 0);
      }
    }
#pragma unroll
    for (int j = 0; j < 8; ++j)
#pragma unroll
      for (int r = 0; r < 4; ++r) {
        int row = wave * 16 + g * 4 + r;
        s_hf[row * 132 + j * 16 + r15] = fmaxf(h1[j][r], 0.f);
      }
    __syncthreads();
    {
      int row = t >> 2, q = t & 3;
      float p = 0.f;
#pragma unroll
      for (int c = 0; c < 32; ++c) {
        int col = q * 32 + c;
        p = fmaf(s_hf[row * 132 + col], Wec2[col], p);
      }
      p += __shfl_down(p, 1, 64);
      p += __shfl_down(p, 2, 64);
      if (q == 0) preds_edge[r0 + row] = p + bec2[0];
    }
    return;
  }

  // ---------------- node classification head (VALU) ------------------------
  float* s_a = (float*)smem;               // [8][128]
  float* s_h = (float*)(smem + 4096);      // [8][128]
  const int r0 = (blockIdx.x - 3125) * 8;
  for (int idx = t; idx < 1024; idx += 256) {
    int r = idx >> 7, k = idx & 127;
    s_a[r * 128 + k] = bf2f(nf[(size_t)(r0 + r) * 128 + k]);
  }
  __syncthreads();
  const int c = t & 127, g = t >> 7;
  float acc[4];
#pragma unroll
  for (int e = 0; e < 4; ++e) acc[e] = bnc1[c];
  for (int k = 0; k < 128; ++k) {
    float w = Wnc1[(size_t)k * 128 + c];
#pragma unroll
    for (int e = 0; e < 4; ++e) acc[e] = fmaf(s_a[(g * 4 + e) * 128 + k], w, acc[e]);
  }
#pragma unroll
  for (int e = 0; e < 4; ++e) s_h[(g * 4 + e) * 128 + c] = fmaxf(acc[e], 0.f);
  __syncthreads();

  const int wave = t >> 6, lane = t & 63;
#pragma unroll
  for (int e2 = 0; e2 < 2; ++e2) {
    int r = wave * 2 + e2;
    float p = s_h[r * 128 + lane] * Wnc2[lane] + s_h[r * 128 + lane + 64] * Wnc2[lane + 64];
#pragma unroll
    for (int off = 32; off; off >>= 1) p += __shfl_down(p, off, 64);
    if (lane == 0) preds_node[r0 + r] = p + bnc2[0];
  }
}

// ---------------------------------------------------------------------------
// prep_all (per step): blocks [0,1413) per-node precompute Ppack (MFMA);
// blocks [1413,2663) zero agg. Absorbs the hipMemsetAsync dispatch.
// ---------------------------------------------------------------------------
__global__ __launch_bounds__(256) void prep_all(
    const ushort* __restrict__ nf0, const ushort* __restrict__ nf,
    const ushort* __restrict__ Wsp, ushort* __restrict__ Ppack,
    float* __restrict__ agg)
{
  const int t = threadIdx.x;
  if (blockIdx.x >= 1413) {
    size_t i = (size_t)(blockIdx.x - 1413) * 256 + t;   // uint4 index, 320000 total
    ((uint4*)agg)[i] = (uint4){0u, 0u, 0u, 0u};
    return;
  }
  __shared__ char s_a[64 * 512];   // [64][256] bf16 swizzled
  const int bx = blockIdx.x % 157;
  const int r0 = bx * 64;
  const int cc = (blockIdx.x / 157) * 128;

  for (int idx = t; idx < 64 * 32; idx += 256) {
    int r = idx >> 5, c = idx & 31;
    int n = r0 + r; if (n >= N_NODES) n = N_NODES - 1;
    const ushort* base = (c < 16 ? nf0 : nf) + (size_t)n * 128 + (c & 15) * 8;
    *(uint4*)(s_a + ((r * 512 + c * 16) ^ ((r & 7) << 4))) = *(const uint4*)base;
  }
  __syncthreads();

  const int lane = t & 63, wave = t >> 6;
  const int r15 = lane & 15, g = lane >> 4;
  const int swz = (r15 & 7) << 4;

  f32x4 acc[8];
#pragma unroll
  for (int j = 0; j < 8; ++j) acc[j] = (f32x4){0.f, 0.f, 0.f, 0.f};
#pragma unroll
  for (int kt = 0; kt < 8; ++kt) {
    short8 a = *(const short8*)(s_a + (((wave * 16 + r15) * 512 + kt * 64 + g * 16) ^ swz));
    const ushort* wk = Wsp + (size_t)kt * 36864 + (size_t)(cc + r15) * 32 + g * 8;
#pragma unroll
    for (int j = 0; j < 8; ++j) {
      short8 b = *(const short8*)(wk + j * 512);
      acc[j] = __builtin_amdgcn_mfma_f32_16x16x32_bf16(a, b, acc[j], 0, 0, 0);
    }
  }
#pragma unroll
  for (int j = 0; j < 8; ++j)
#pragma unroll
    for (int r = 0; r < 4; ++r) {
      int row = r0 + wave * 16 + g * 4 + r;
      if (row < N_NODES)
        Ppack[(size_t)row * 1152 + cc + j * 16 + r15] = f2bf(acc[j][r]);
    }
}

// ---------------------------------------------------------------------------
// Fused per-step edge kernel — EXACT R8 config (best measured: 240 us).
// TE=32 edges/block, 512 thr/8 waves, LDS 58.4 KB -> 2 blocks/CU.
//   stage: A=[ef0|efA] K=256 -> s_a; sP=P_i+P_j -> s_h; Q -> s_q
//   GEMM1: h = relu(sP + A@W1e + be1)   K=256 -> s_h (own cols, in place)
//   GEMM2: e = relu(h@We2 + be2)        K=512 -> s_a + global ef
//   GEMM3: m = relu(Q + e@W3e + bn1)    K=128 -> atomicAdd agg[i]
// ---------------------------------------------------------------------------
__global__ __launch_bounds__(512, 4) void fused_edge_mfma(
    const ushort* __restrict__ Ppack,
    const ushort* __restrict__ ef0, const ushort* __restrict__ efA,
    ushort* __restrict__ ef,
    const int* __restrict__ ei,
    const ushort* __restrict__ W1ep, const float* __restrict__ be1,
    const ushort* __restrict__ W2p,  const float* __restrict__ be2,
    const ushort* __restrict__ W3ep, const float* __restrict__ bn1,
    float* __restrict__ agg)
{
  __shared__ __align__(16) char s_a[TE * 512];     // 16 KB: A panel, later e
  __shared__ __align__(16) char s_h[TE * 1024];    // 32 KB: sP, then h
  __shared__ __align__(16) ushort s_q[TE * 136];   // 8.7 KB: Q rows (pad 136)
  __shared__ int s_i[TE], s_j[TE];

  const int t = threadIdx.x;
  // bijective XCD swizzle: NWG=6250, q=781, rr=2
  const int NWG = N_EDGES / TE;
  const int q = NWG / 8, rr = NWG % 8;
  int xcd = blockIdx.x & 7, bidx = blockIdx.x >> 3;
  int wgid = (xcd < rr ? xcd * (q + 1) : rr * (q + 1) + (xcd - rr) * q) + bidx;
  const int e0 = wgid * TE;

  if (t < TE) s_j[t] = ei[e0 + t];
  else if (t < 2 * TE) s_i[t - TE] = ei[N_EDGES + e0 + (t - TE)];
  __syncthreads();

  // ---- stage A panel [TE][256] = [ef0|efA] (bf16, swizzled) ----
  for (int idx = t; idx < TE * 32; idx += 512) {
    int e = idx >> 5, c = idx & 31;
    const ushort* base = (c < 16 ? ef0 : efA) + (size_t)(e0 + e) * 128 + (c & 15) * 8;
    *(uint4*)(s_a + ((e * 512 + c * 16) ^ ((e & 7) << 4))) = *(const uint4*)base;
  }
  // ---- stage sP = P_i + P_j (f32 add, packed bf16 store) into s_h ----
  for (int idx = t; idx < TE * 64; idx += 512) {
    int e = idx >> 6, c = idx & 63;
    uint4 vi = *(const uint4*)(Ppack + (size_t)s_i[e] * 1152 + c * 8);
    uint4 vj = *(const uint4*)(Ppack + (size_t)s_j[e] * 1152 + 512 + c * 8);
    const ushort* pa = (const ushort*)&vi;
    const ushort* pb = (const ushort*)&vj;
    uint o4[4];
#pragma unroll
    for (int z = 0; z < 4; ++z)
      o4[z] = pk2bf(bf2f(pa[2 * z]) + bf2f(pb[2 * z]),
                    bf2f(pa[2 * z + 1]) + bf2f(pb[2 * z + 1]));
    *(uint4*)(s_h + ((e * 1024 + c * 16) ^ ((e & 7) << 4))) = *(uint4*)o4;
  }
  // ---- stage sQ = Q[i] ----
  {
    int e = t >> 4, c = t & 15;    // t < 512 = TE*16 exactly
    uint4 v = *(const uint4*)(Ppack + (size_t)s_i[e] * 1152 + 1024 + c * 8);
    *(uint4*)((char*)s_q + e * 272 + c * 16) = v;
  }
  __syncthreads();

  const int lane = t & 63, wave = t >> 6;
  const int r15 = lane & 15, g = lane >> 4;
  const int swz = (r15 & 7) << 4;
  const int wb = wave * 64, wb2 = wave * 16;

  // ================= GEMM1: K=256, per-wave N=64, init from sP ============
  f32x4 acc1[2][4];
#pragma unroll
  for (int j = 0; j < 4; ++j) {
    float bv = be1[wb + j * 16 + r15];
#pragma unroll
    for (int mt = 0; mt < 2; ++mt)
#pragma unroll
      for (int r = 0; r < 4; ++r) {
        int row = mt * 16 + g * 4 + r;
        int col = wb + j * 16 + r15;
        ushort u = *(const ushort*)(s_h + ((row * 1024 + col * 2) ^ ((row & 7) << 4)));
        acc1[mt][j][r] = bv + bf2f(u);
      }
  }
  {
    const ushort* wkb = W1ep + (size_t)(wb + r15) * 32 + g * 8;
    short8 bc[4], bn[4];
#pragma unroll
    for (int j = 0; j < 4; ++j) bc[j] = *(const short8*)(wkb + j * 512);
    for (int kt = 0; kt < 8; ++kt) {
      short8 a0 = *(const short8*)(s_a + ((r15 * 512 + kt * 64 + g * 16) ^ swz));
      short8 a1 = *(const short8*)(s_a + (((r15 + 16) * 512 + kt * 64 + g * 16) ^ swz));
      const ushort* wnx = wkb + (size_t)(kt + 1) * 16384;  // slack-padded
#pragma unroll
      for (int j = 0; j < 4; ++j) bn[j] = *(const short8*)(wnx + j * 512);
#pragma unroll
      for (int j = 0; j < 4; ++j) {
        acc1[0][j] = __builtin_amdgcn_mfma_f32_16x16x32_bf16(a0, bc[j], acc1[0][j], 0, 0, 0);
        acc1[1][j] = __builtin_amdgcn_mfma_f32_16x16x32_bf16(a1, bc[j], acc1[1][j], 0, 0, 0);
      }
#pragma unroll
      for (int j = 0; j < 4; ++j) bc[j] = bn[j];
    }
  }
  // h write (each wave overwrites only its own columns of s_h)
#pragma unroll
  for (int mt = 0; mt < 2; ++mt)
#pragma unroll
    for (int j = 0; j < 4; ++j)
#pragma unroll
      for (int r = 0; r < 4; ++r) {
        int row = mt * 16 + g * 4 + r;
        int col = wb + j * 16 + r15;
        *(ushort*)(s_h + ((row * 1024 + col * 2) ^ ((row & 7) << 4))) =
            f2bf(fmaxf(acc1[mt][j][r], 0.f));
      }
  __syncthreads();

  // ===== GEMM2: K=512, per-wave N=16, K-split accs + depth-2 B prefetch ===
  f32x4 acc2[2], acc2b[2];
  {
    float bv = be2[wb2 + r15];
    acc2[0] = (f32x4){bv, bv, bv, bv};
    acc2[1] = (f32x4){bv, bv, bv, bv};
    acc2b[0] = (f32x4){0.f, 0.f, 0.f, 0.f};
    acc2b[1] = (f32x4){0.f, 0.f, 0.f, 0.f};
  }
  {
    const ushort* wkb = W2p + (size_t)(wb2 + r15) * 32 + g * 8;
    short8 bA = *(const short8*)(wkb);
    short8 bB = *(const short8*)(wkb + 4096);
    for (int kt2 = 0; kt2 < 8; ++kt2) {
      int ab0 = (2 * kt2) * 64 + g * 16;
      int ab1 = ab0 + 64;
      short8 a0e = *(const short8*)(s_h + ((r15 * 1024 + ab0) ^ swz));
      short8 a1e = *(const short8*)(s_h + (((r15 + 16) * 1024 + ab0) ^ swz));
      short8 a0o = *(const short8*)(s_h + ((r15 * 1024 + ab1) ^ swz));
      short8 a1o = *(const short8*)(s_h + (((r15 + 16) * 1024 + ab1) ^ swz));
      short8 bAn = *(const short8*)(wkb + (size_t)(2 * kt2 + 2) * 4096);  // slack
      short8 bBn = *(const short8*)(wkb + (size_t)(2 * kt2 + 3) * 4096);  // slack
      acc2[0]  = __builtin_amdgcn_mfma_f32_16x16x32_bf16(a0e, bA, acc2[0], 0, 0, 0);
      acc2b[0] = __builtin_amdgcn_mfma_f32_16x16x32_bf16(a0o, bB, acc2b[0], 0, 0, 0);
      acc2[1]  = __builtin_amdgcn_mfma_f32_16x16x32_bf16(a1e, bA, acc2[1], 0, 0, 0);
      acc2b[1] = __builtin_amdgcn_mfma_f32_16x16x32_bf16(a1o, bB, acc2b[1], 0, 0, 0);
      bA = bAn; bB = bBn;
    }
    acc2[0] = acc2[0] + acc2b[0];
    acc2[1] = acc2[1] + acc2b[1];
  }
  // e write into s_a (own cols; s_a dead after GEMM1)
#pragma unroll
  for (int mt = 0; mt < 2; ++mt)
#pragma unroll
    for (int r = 0; r < 4; ++r) {
      int row = mt * 16 + g * 4 + r;
      int col = wb2 + r15;
      *(ushort*)(s_a + ((row * 512 + col * 2) ^ ((row & 7) << 4))) =
          f2bf(fmaxf(acc2[mt][r], 0.f));
    }
  __syncthreads();

  // coalesced e -> global ef (bf16)
  {
    int e = t >> 4, c = t & 15;
    uint4 v = *(const uint4*)(s_a + ((e * 512 + c * 16) ^ ((e & 7) << 4)));
    *(uint4*)(ef + (size_t)(e0 + e) * 128 + c * 8) = v;
  }

  // ================= GEMM3: K=128 (e part), init from sQ ==================
  f32x4 acc3[2];
  {
    float bv = bn1[wb2 + r15];
#pragma unroll
    for (int mt = 0; mt < 2; ++mt)
#pragma unroll
      for (int r = 0; r < 4; ++r) {
        int row = mt * 16 + g * 4 + r;
        acc3[mt][r] = bv + bf2f(s_q[row * 136 + wb2 + r15]);
      }
  }
  {
    const ushort* w3b = W3ep + (size_t)(wb2 + r15) * 32 + g * 8;
    short8 bq[4];
#pragma unroll
    for (int kk = 0; kk < 4; ++kk) bq[kk] = *(const short8*)(w3b + (size_t)kk * 4096);
#pragma unroll
    for (int kk = 0; kk < 4; ++kk) {
      short8 a0 = *(const short8*)(s_a + ((r15 * 512 + kk * 64 + g * 16) ^ swz));
      short8 a1 = *(const short8*)(s_a + (((r15 + 16) * 512 + kk * 64 + g * 16) ^ swz));
      acc3[0] = __builtin_amdgcn_mfma_f32_16x16x32_bf16(a0, bq[kk], acc3[0], 0, 0, 0);
      acc3[1] = __builtin_amdgcn_mfma_f32_16x16x32_bf16(a1, bq[kk], acc3[1], 0, 0, 0);
    }
  }
  // scatter-add messages to agg (f32 atomics)
#pragma unroll
  for (int mt = 0; mt < 2; ++mt)
#pragma unroll
    for (int r = 0; r < 4; ++r) {
      int row = mt * 16 + g * 4 + r;
      int node = s_i[row];
      atomicAdd(&agg[(size_t)node * 128 + wb2 + r15], fmaxf(acc3[mt][r], 0.f));
    }
}

// ---------------------------------------------------------------------------
extern "C" void kernel_launch(void* const* d_in, const int* in_sizes, int n_in,
                              void* d_out, int out_size, void* d_ws, size_t ws_size,
                              hipStream_t stream) {
  const float* x         = (const float*)d_in[0];
  const float* edge_attr = (const float*)d_in[1];
  const int*   ei        = (const int*)d_in[2];
  const float* Wne1 = (const float*)d_in[3];  const float* bne1 = (const float*)d_in[4];
  const float* Wne2 = (const float*)d_in[5];  const float* bne2 = (const float*)d_in[6];
  const float* Wee1 = (const float*)d_in[7];  const float* bee1 = (const float*)d_in[8];
  const float* Wee2 = (const float*)d_in[9];  const float* bee2 = (const float*)d_in[10];
  const float* We1  = (const float*)d_in[11]; const float* be1  = (const float*)d_in[12];
  const float* We2  = (const float*)d_in[13]; const float* be2  = (const float*)d_in[14];
  const float* Wn1  = (const float*)d_in[15]; const float* bn1  = (const float*)d_in[16];
  const float* Wu   = (const float*)d_in[17]; const float* bu   = (const float*)d_in[18];
  const float* Wnc1 = (const float*)d_in[19]; const float* bnc1 = (const float*)d_in[20];
  const float* Wnc2 = (const float*)d_in[21]; const float* bnc2 = (const float*)d_in[22];
  const float* Wec1 = (const float*)d_in[23]; const float* bec1 = (const float*)d_in[24];
  const float* Wec2 = (const float*)d_in[25]; const float* bec2 = (const float*)d_in[26];

  float* preds_edge = (float*)d_out;         // [E]
  float* preds_node = preds_edge + N_EDGES;  // [N]

  char* w = (char*)d_ws;
  ushort* nf0  = (ushort*)w; w += (size_t)N_NODES * 128 * 2;
  ushort* nf   = (ushort*)w; w += (size_t)N_NODES * 128 * 2;
  ushort* ef0  = (ushort*)w; w += (size_t)N_EDGES * 128 * 2;
  ushort* ef   = (ushort*)w; w += (size_t)N_EDGES * 128 * 2;
  float*  agg  = (float*)w;  w += (size_t)N_NODES * 128 * 4;
  ushort* Ppack = (ushort*)w; w += (size_t)N_NODES * 1152 * 2;   // 23 MB
  ushort* Wsp  = (ushort*)w; w += (size_t)8 * 1152 * 32 * 2;     // 256x1152
  ushort* W1ep = (ushort*)w; w += (size_t)9 * 512 * 32 * 2;      // +1kt slack
  ushort* W2p  = (ushort*)w; w += (size_t)18 * 128 * 32 * 2;     // +2kt slack
  ushort* W3ep = (ushort*)w; w += (size_t)4 * 128 * 32 * 2;
  ushort* Wee1p = (ushort*)w; w += (size_t)64 * 128 * 2;
  ushort* Wee2p = (ushort*)w; w += (size_t)128 * 128 * 2;
  ushort* Wec1p = (ushort*)w; w += (size_t)128 * 128 * 2;
  // total ~138 MB

  permute_all<<<2144, 256, 0, stream>>>(
      We1, We2, Wn1, Wee1, Wee2, Wec1,
      Wsp, W1ep, W2p, W3ep, Wee1p, Wee2p, Wec1p);

  embed_all<<<1250 + 3125, 256, 0, stream>>>(
      x, Wne1, bne1, Wne2, bne2,
      edge_attr, Wee1p, bee1, Wee2p, bee2, nf0, nf, ef0);

  for (int s = 0; s < 2; ++s) {
    prep_all<<<1413 + 1250, 256, 0, stream>>>(nf0, nf, Wsp, Ppack, agg);
    fused_edge_mfma<<<N_EDGES / TE, 512, 0, stream>>>(
        Ppack, ef0, (s == 0 ? ef0 : ef), ef, ei,
        W1ep, be1, W2p, be2, W3ep, bn1, agg);
    mlp1_kernel<<<(N_NODES + 7) / 8, 256, 0, stream>>>(agg, N_NODES, Wu, bu, nf);
  }

  head_all<<<3125 + 1250, 256, 0, stream>>>(
      ef, Wec1p, bec1, Wec2, bec2,
      nf, Wnc1, bnc1, Wnc2, bnc2, preds_edge, preds_node);
}